// Round 2
// baseline (4895.658 us; speedup 1.0000x reference)
//
#include <hip/hip_runtime.h>
#include <stdint.h>

#define NN 100000
#define NE 3200000
#define NBK 782          // ceil(NN/128) buckets of 128 dst nodes

typedef unsigned int uint;
typedef unsigned short ushort;
typedef __attribute__((ext_vector_type(8))) short bf16x8;
typedef __attribute__((ext_vector_type(4))) float f32x4;

static __device__ __forceinline__ float bflo(uint v) {
    uint u = v << 16; return __builtin_bit_cast(float, u);
}
static __device__ __forceinline__ float bfhi(uint v) {
    uint u = v & 0xffff0000u; return __builtin_bit_cast(float, u);
}
static __device__ __forceinline__ float b2f(ushort v) {
    uint u = ((uint)v) << 16; return __builtin_bit_cast(float, u);
}
static __device__ __forceinline__ ushort f2b(float f) {  // RNE fp32->bf16
    uint u = __builtin_bit_cast(uint, f);
    u += 0x7fffu + ((u >> 16) & 1u);
    return (ushort)(u >> 16);
}

// ---------------- bucket build ----------------
// Per-block LDS histogram -> few global atomics (782 counters are too hot
// for 3.2M direct global atomics).
__global__ __launch_bounds__(256) void bhist_k(const int* __restrict__ dst,
                                               int* __restrict__ bcnt) {
    __shared__ int hl[NBK];
    for (int i = threadIdx.x; i < NBK; i += 256) hl[i] = 0;
    __syncthreads();
    int i = blockIdx.x * 256 + threadIdx.x;
    int stride = gridDim.x * 256;
    for (; i < NE; i += stride)
        atomicAdd(&hl[dst[i] >> 7], 1);
    __syncthreads();
    for (int i = threadIdx.x; i < NBK; i += 256)
        if (hl[i]) atomicAdd(&bcnt[i], hl[i]);
}

// single-block scan of NBK counts -> bbase (exclusive), bcur = bbase copy
__global__ __launch_bounds__(1024) void bscan_k(const int* __restrict__ bcnt,
                                                int* __restrict__ bbase,
                                                int* __restrict__ bcur) {
    __shared__ int sd[1024];
    int t = threadIdx.x;
    int v = (t < NBK) ? bcnt[t] : 0;
    sd[t] = v;
    __syncthreads();
    for (int off = 1; off < 1024; off <<= 1) {
        int u = (t >= off) ? sd[t - off] : 0;
        __syncthreads();
        sd[t] += u;
        __syncthreads();
    }
    int excl = sd[t] - v;
    if (t < NBK) { bbase[t] = excl; bcur[t] = excl; }
}

// scatter packed edge words into buckets. Active write set = 782 tail lines
// (~50KB, L2-resident) -> ~13MB writes instead of 195MB.
__global__ __launch_bounds__(256) void bfill_k(const int* __restrict__ ei,
                                               int* __restrict__ bcur,
                                               uint* __restrict__ barr) {
    int i = blockIdx.x * 256 + threadIdx.x;
    int stride = gridDim.x * 256;
    for (; i < NE; i += stride) {
        int s = ei[i];
        int d = ei[NE + i];
        int pos = atomicAdd(&bcur[d >> 7], 1);
        barr[pos] = ((uint)(d & 127) << 17) | (uint)s;
    }
}

// ---------------- GEMM1: y1 = bf16( x @ W1^T ), x fp32 [NN,128] ----------------
__global__ __launch_bounds__(256) void gemm1_k(const float* __restrict__ x,
                                               const float* __restrict__ W1,
                                               ushort* __restrict__ y1) {
    __shared__ ushort wl[128 * 136];
    int tid = threadIdx.x;
    for (int i = tid; i < 128 * 128; i += 256)
        wl[(i >> 7) * 136 + (i & 127)] = f2b(W1[i]);
    __syncthreads();

    int wave = tid >> 6, lane = tid & 63;
    int lr = lane & 15, lk = (lane >> 4) * 8;
    long rowbase = (long)blockIdx.x * 128 + wave * 32;

    f32x4 acc[2][8] = {};
    for (int kc = 0; kc < 128; kc += 32) {
        bf16x8 a[2];
#pragma unroll
        for (int m = 0; m < 2; m++) {
            long row = rowbase + m * 16 + lr;
            if (row > NN - 1) row = NN - 1;
            const float* p = x + row * 128 + kc + lk;
            float f[8];
            *(float4*)(f)     = *(const float4*)(p);
            *(float4*)(f + 4) = *(const float4*)(p + 4);
            bf16x8 t;
#pragma unroll
            for (int j = 0; j < 8; j++) t[j] = (short)f2b(f[j]);
            a[m] = t;
        }
#pragma unroll
        for (int nb = 0; nb < 8; nb++) {
            bf16x8 b = *(const bf16x8*)&wl[(nb * 16 + lr) * 136 + kc + lk];
            acc[0][nb] = __builtin_amdgcn_mfma_f32_16x16x32_bf16(a[0], b, acc[0][nb], 0, 0, 0);
            acc[1][nb] = __builtin_amdgcn_mfma_f32_16x16x32_bf16(a[1], b, acc[1][nb], 0, 0, 0);
        }
    }
    int rq = (lane >> 4) * 4;
#pragma unroll
    for (int m = 0; m < 2; m++) {
#pragma unroll
        for (int r = 0; r < 4; r++) {
            long row = rowbase + m * 16 + rq + r;
            if (row < NN) {
#pragma unroll
                for (int nb = 0; nb < 8; nb++)
                    y1[row * 128 + nb * 16 + lr] = f2b(acc[m][nb][r]);
            }
        }
    }
}

// ---------------- GEMM2: y2 = bf16( h @ W2^T ), h bf16 [NN,128], W2 [64,128] ----------------
__global__ __launch_bounds__(256) void gemm2_k(const ushort* __restrict__ h,
                                               const float* __restrict__ W2,
                                               ushort* __restrict__ y2) {
    __shared__ ushort wl[64 * 136];
    int tid = threadIdx.x;
    for (int i = tid; i < 64 * 128; i += 256)
        wl[(i >> 7) * 136 + (i & 127)] = f2b(W2[i]);
    __syncthreads();

    int wave = tid >> 6, lane = tid & 63;
    int lr = lane & 15, lk = (lane >> 4) * 8;
    long rowbase = (long)blockIdx.x * 128 + wave * 32;

    f32x4 acc[2][4] = {};
    for (int kc = 0; kc < 128; kc += 32) {
        bf16x8 a[2];
#pragma unroll
        for (int m = 0; m < 2; m++) {
            long row = rowbase + m * 16 + lr;
            if (row > NN - 1) row = NN - 1;
            a[m] = *(const bf16x8*)(h + row * 128 + kc + lk);
        }
#pragma unroll
        for (int nb = 0; nb < 4; nb++) {
            bf16x8 b = *(const bf16x8*)&wl[(nb * 16 + lr) * 136 + kc + lk];
            acc[0][nb] = __builtin_amdgcn_mfma_f32_16x16x32_bf16(a[0], b, acc[0][nb], 0, 0, 0);
            acc[1][nb] = __builtin_amdgcn_mfma_f32_16x16x32_bf16(a[1], b, acc[1][nb], 0, 0, 0);
        }
    }
    int rq = (lane >> 4) * 4;
#pragma unroll
    for (int m = 0; m < 2; m++) {
#pragma unroll
        for (int r = 0; r < 4; r++) {
            long row = rowbase + m * 16 + rq + r;
            if (row < NN) {
#pragma unroll
                for (int nb = 0; nb < 4; nb++)
                    y2[row * 64 + nb * 16 + lr] = f2b(acc[m][nb][r]);
            }
        }
    }
}

// ---------------- fused bucket aggregation ----------------
// One WG (512 thr / 8 waves) per bucket of 128 nodes. fp32 accumulator in
// LDS; gathers of y[src] coalesced; ds_add_f32 at lane%32 banks (2-way=free).

__global__ __launch_bounds__(512) void agg1f_k(const ushort* __restrict__ y1,
                                               const int* __restrict__ bbase,
                                               const int* __restrict__ bend,
                                               const uint* __restrict__ barr,
                                               const float* __restrict__ b1,
                                               ushort* __restrict__ h) {
    __shared__ float acc[128 * 128];   // 64KB
    int tid = threadIdx.x;
    for (int i = tid; i < 128 * 128; i += 512) acc[i] = 0.f;
    __syncthreads();

    int blk = blockIdx.x;
    int s0 = bbase[blk], s1 = bend[blk];
    int wave = tid >> 6, lane = tid & 63;

    for (int i = s0 + wave * 64; i < s1; i += 512) {
        int m = s1 - i; if (m > 64) m = 64;
        uint w = (lane < m) ? barr[i + lane] : 0;
        for (int j = 0; j < m; j++) {
            uint e = __shfl(w, j);
            int src = e & 0x1FFFF;
            int nl = e >> 17;
            const ushort* p = y1 + (size_t)src * 128;
            float f0 = b2f(p[lane]);
            float f1 = b2f(p[64 + lane]);
            atomicAdd(&acc[nl * 128 + lane], f0);
            atomicAdd(&acc[nl * 128 + 64 + lane], f1);
        }
    }
    __syncthreads();

    int nodebase = blk * 128;
    for (int i = tid; i < 128 * 64; i += 512) {
        int nl = i >> 6, dp = i & 63;
        int node = nodebase + nl;
        if (node < NN) {
            uint v = *(const uint*)(y1 + (size_t)node * 128 + 2 * dp);
            float a0 = acc[nl * 128 + 2 * dp]     + bflo(v) + b1[2 * dp];
            float a1 = acc[nl * 128 + 2 * dp + 1] + bfhi(v) + b1[2 * dp + 1];
            a0 = fmaxf(a0, 0.f);
            a1 = fmaxf(a1, 0.f);
            *(uint*)(h + (size_t)node * 128 + 2 * dp) = (uint)f2b(a0) | ((uint)f2b(a1) << 16);
        }
    }
}

__global__ __launch_bounds__(512) void agg2f_k(const ushort* __restrict__ y2,
                                               const int* __restrict__ bbase,
                                               const int* __restrict__ bend,
                                               const uint* __restrict__ barr,
                                               const float* __restrict__ b2,
                                               float* __restrict__ out) {
    __shared__ float acc[128 * 64];    // 32KB
    int tid = threadIdx.x;
    for (int i = tid; i < 128 * 64; i += 512) acc[i] = 0.f;
    __syncthreads();

    int blk = blockIdx.x;
    int s0 = bbase[blk], s1 = bend[blk];
    int wave = tid >> 6, lane = tid & 63;

    for (int i = s0 + wave * 64; i < s1; i += 512) {
        int m = s1 - i; if (m > 64) m = 64;
        uint w = (lane < m) ? barr[i + lane] : 0;
        for (int j = 0; j < m; j++) {
            uint e = __shfl(w, j);
            int src = e & 0x1FFFF;
            int nl = e >> 17;
            float f = b2f(y2[(size_t)src * 64 + lane]);
            atomicAdd(&acc[nl * 64 + lane], f);
        }
    }
    __syncthreads();

    int nodebase = blk * 128;
    for (int i = tid; i < 128 * 64; i += 512) {
        int nl = i >> 6, d = i & 63;
        int node = nodebase + nl;
        if (node < NN)
            out[(size_t)node * 64 + d] = acc[nl * 64 + d] + b2f(y2[(size_t)node * 64 + d]) + b2[d];
    }
}

// ---------------- launch ----------------

static constexpr size_t alup(size_t x) { return (x + 255) & ~(size_t)255; }
static constexpr size_t OFF_BCNT  = 0;
static constexpr size_t OFF_BBASE = alup(OFF_BCNT  + NBK * 4);
static constexpr size_t OFF_BCUR  = alup(OFF_BBASE + NBK * 4);
static constexpr size_t OFF_BARR  = alup(OFF_BCUR  + NBK * 4);
static constexpr size_t OFF_Y1    = alup(OFF_BARR  + (size_t)NE * 4);
static constexpr size_t OFF_H     = alup(OFF_Y1 + (size_t)NN * 128 * 2);
static constexpr size_t OFF_Y2    = alup(OFF_H  + (size_t)NN * 128 * 2);

extern "C" void kernel_launch(void* const* d_in, const int* in_sizes, int n_in,
                              void* d_out, int out_size, void* d_ws, size_t ws_size,
                              hipStream_t stream) {
    const float* x  = (const float*)d_in[0];
    const int*   ei = (const int*)d_in[1];
    const float* W1 = (const float*)d_in[2];
    const float* b1 = (const float*)d_in[3];
    const float* W2 = (const float*)d_in[4];
    const float* b2 = (const float*)d_in[5];
    float* out = (float*)d_out;
    char* ws = (char*)d_ws;

    int*  bcnt  = (int*)(ws + OFF_BCNT);
    int*  bbase = (int*)(ws + OFF_BBASE);
    int*  bcur  = (int*)(ws + OFF_BCUR);
    uint* barr  = (uint*)(ws + OFF_BARR);
    ushort* y1 = (ushort*)(ws + OFF_Y1);
    ushort* hh = (ushort*)(ws + OFF_H);
    ushort* y2 = (ushort*)(ws + OFF_Y2);

    hipMemsetAsync(bcnt, 0, NBK * sizeof(int), stream);
    hipLaunchKernelGGL(bhist_k, dim3(256),  dim3(256),  0, stream, ei + NE, bcnt);
    hipLaunchKernelGGL(bscan_k, dim3(1),    dim3(1024), 0, stream, bcnt, bbase, bcur);
    hipLaunchKernelGGL(bfill_k, dim3(2048), dim3(256),  0, stream, ei, bcur, barr);

    hipLaunchKernelGGL(gemm1_k, dim3(782), dim3(256), 0, stream, x, W1, y1);
    hipLaunchKernelGGL(agg1f_k, dim3(NBK), dim3(512), 0, stream, y1, bbase, bcur, barr, b1, hh);
    hipLaunchKernelGGL(gemm2_k, dim3(782), dim3(256), 0, stream, hh, W2, y2);
    hipLaunchKernelGGL(agg2f_k, dim3(NBK), dim3(512), 0, stream, y2, bbase, bcur, barr, b2, out);
}

// Round 3
// 1188.727 us; speedup vs baseline: 4.1184x; 4.1184x over previous
//
#include <hip/hip_runtime.h>
#include <stdint.h>

#define NN 100000
#define NE 3200000
#define NBK 782          // ceil(NN/128) buckets of 128 dst nodes

typedef unsigned int uint;
typedef unsigned short ushort;
typedef __attribute__((ext_vector_type(8))) short bf16x8;
typedef __attribute__((ext_vector_type(4))) float f32x4;

static __device__ __forceinline__ float bflo(uint v) {
    uint u = v << 16; return __builtin_bit_cast(float, u);
}
static __device__ __forceinline__ float bfhi(uint v) {
    uint u = v & 0xffff0000u; return __builtin_bit_cast(float, u);
}
static __device__ __forceinline__ float b2f(ushort v) {
    uint u = ((uint)v) << 16; return __builtin_bit_cast(float, u);
}
static __device__ __forceinline__ ushort f2b(float f) {  // RNE fp32->bf16
    uint u = __builtin_bit_cast(uint, f);
    u += 0x7fffu + ((u >> 16) & 1u);
    return (ushort)(u >> 16);
}

// ---------------- bucket build ----------------

__global__ __launch_bounds__(256) void bhist_k(const int* __restrict__ dst,
                                               int* __restrict__ bcnt) {
    __shared__ int hl[NBK];
    for (int i = threadIdx.x; i < NBK; i += 256) hl[i] = 0;
    __syncthreads();
    int i = blockIdx.x * 256 + threadIdx.x;
    int stride = gridDim.x * 256;
    for (; i < NE; i += stride)
        atomicAdd(&hl[dst[i] >> 7], 1);
    __syncthreads();
    for (int i = threadIdx.x; i < NBK; i += 256)
        if (hl[i]) atomicAdd(&bcnt[i], hl[i]);
}

// single-block scan of NBK counts -> bbase (exclusive), bcur = copy; nodeptr[NN]=NE
__global__ __launch_bounds__(1024) void bscan_k(const int* __restrict__ bcnt,
                                                int* __restrict__ bbase,
                                                int* __restrict__ bcur,
                                                int* __restrict__ nodeptr) {
    __shared__ int sd[1024];
    int t = threadIdx.x;
    int v = (t < NBK) ? bcnt[t] : 0;
    sd[t] = v;
    __syncthreads();
    for (int off = 1; off < 1024; off <<= 1) {
        int u = (t >= off) ? sd[t - off] : 0;
        __syncthreads();
        sd[t] += u;
        __syncthreads();
    }
    int excl = sd[t] - v;
    if (t < NBK) { bbase[t] = excl; bcur[t] = excl; }
    if (t == 0) nodeptr[NN] = NE;
}

// scatter packed (nodeLocal<<17 | src) into bucket regions. Active write set =
// 782 tail lines (~50KB, L2-resident).
__global__ __launch_bounds__(256) void bfill_k(const int* __restrict__ ei,
                                               int* __restrict__ bcur,
                                               uint* __restrict__ barr) {
    int i = blockIdx.x * 256 + threadIdx.x;
    int stride = gridDim.x * 256;
    for (; i < NE; i += stride) {
        int s = ei[i];
        int d = ei[NE + i];
        int pos = atomicAdd(&bcur[d >> 7], 1);
        barr[pos] = ((uint)(d & 127) << 17) | (uint)s;
    }
}

// within-bucket counting sort -> exact CSR (src-only) + nodeptr.
// One WG per bucket; writes stay inside the bucket's contiguous 16KB window.
__global__ __launch_bounds__(256) void csr_k(const uint* __restrict__ barr,
                                             const int* __restrict__ bbase,
                                             const int* __restrict__ bend,
                                             int* __restrict__ nodeptr,
                                             uint* __restrict__ col) {
    __shared__ int cnt[128], cur[128];
    int tid = threadIdx.x;
    int blk = blockIdx.x;
    int s0 = bbase[blk], s1 = bend[blk];
    if (tid < 128) cnt[tid] = 0;
    __syncthreads();
    for (int i = s0 + tid; i < s1; i += 256)
        atomicAdd(&cnt[barr[i] >> 17], 1);
    __syncthreads();
    if (tid < 64) {
        int c0 = cnt[2 * tid], c1 = cnt[2 * tid + 1];
        int s = c0 + c1;
        int incl = s;
        for (int off = 1; off < 64; off <<= 1) {
            int t = __shfl_up(incl, off);
            if (tid >= off) incl += t;
        }
        int excl = incl - s;
        cur[2 * tid] = excl;
        cur[2 * tid + 1] = excl + c0;
        int node = blk * 128 + 2 * tid;
        if (node < NN)     nodeptr[node]     = s0 + excl;
        if (node + 1 < NN) nodeptr[node + 1] = s0 + excl + c0;
    }
    __syncthreads();
    for (int i = s0 + tid; i < s1; i += 256) {
        uint e = barr[i];
        int pos = s0 + atomicAdd(&cur[e >> 17], 1);
        col[pos] = e & 0x1FFFF;
    }
}

// ---------------- GEMM1: y1 = bf16( x @ W1^T ), x fp32 [NN,128] ----------------
__global__ __launch_bounds__(256) void gemm1_k(const float* __restrict__ x,
                                               const float* __restrict__ W1,
                                               ushort* __restrict__ y1) {
    __shared__ ushort wl[128 * 136];
    int tid = threadIdx.x;
    for (int i = tid; i < 128 * 128; i += 256)
        wl[(i >> 7) * 136 + (i & 127)] = f2b(W1[i]);
    __syncthreads();

    int wave = tid >> 6, lane = tid & 63;
    int lr = lane & 15, lk = (lane >> 4) * 8;
    long rowbase = (long)blockIdx.x * 128 + wave * 32;

    f32x4 acc[2][8] = {};
    for (int kc = 0; kc < 128; kc += 32) {
        bf16x8 a[2];
#pragma unroll
        for (int m = 0; m < 2; m++) {
            long row = rowbase + m * 16 + lr;
            if (row > NN - 1) row = NN - 1;
            const float* p = x + row * 128 + kc + lk;
            float f[8];
            *(float4*)(f)     = *(const float4*)(p);
            *(float4*)(f + 4) = *(const float4*)(p + 4);
            bf16x8 t;
#pragma unroll
            for (int j = 0; j < 8; j++) t[j] = (short)f2b(f[j]);
            a[m] = t;
        }
#pragma unroll
        for (int nb = 0; nb < 8; nb++) {
            bf16x8 b = *(const bf16x8*)&wl[(nb * 16 + lr) * 136 + kc + lk];
            acc[0][nb] = __builtin_amdgcn_mfma_f32_16x16x32_bf16(a[0], b, acc[0][nb], 0, 0, 0);
            acc[1][nb] = __builtin_amdgcn_mfma_f32_16x16x32_bf16(a[1], b, acc[1][nb], 0, 0, 0);
        }
    }
    int rq = (lane >> 4) * 4;
#pragma unroll
    for (int m = 0; m < 2; m++) {
#pragma unroll
        for (int r = 0; r < 4; r++) {
            long row = rowbase + m * 16 + rq + r;
            if (row < NN) {
#pragma unroll
                for (int nb = 0; nb < 8; nb++)
                    y1[row * 128 + nb * 16 + lr] = f2b(acc[m][nb][r]);
            }
        }
    }
}

// ---------------- GEMM2: y2 = bf16( h @ W2^T ), h bf16 [NN,128], W2 [64,128] ----------------
__global__ __launch_bounds__(256) void gemm2_k(const ushort* __restrict__ h,
                                               const float* __restrict__ W2,
                                               ushort* __restrict__ y2) {
    __shared__ ushort wl[64 * 136];
    int tid = threadIdx.x;
    for (int i = tid; i < 64 * 128; i += 256)
        wl[(i >> 7) * 136 + (i & 127)] = f2b(W2[i]);
    __syncthreads();

    int wave = tid >> 6, lane = tid & 63;
    int lr = lane & 15, lk = (lane >> 4) * 8;
    long rowbase = (long)blockIdx.x * 128 + wave * 32;

    f32x4 acc[2][4] = {};
    for (int kc = 0; kc < 128; kc += 32) {
        bf16x8 a[2];
#pragma unroll
        for (int m = 0; m < 2; m++) {
            long row = rowbase + m * 16 + lr;
            if (row > NN - 1) row = NN - 1;
            a[m] = *(const bf16x8*)(h + row * 128 + kc + lk);
        }
#pragma unroll
        for (int nb = 0; nb < 4; nb++) {
            bf16x8 b = *(const bf16x8*)&wl[(nb * 16 + lr) * 136 + kc + lk];
            acc[0][nb] = __builtin_amdgcn_mfma_f32_16x16x32_bf16(a[0], b, acc[0][nb], 0, 0, 0);
            acc[1][nb] = __builtin_amdgcn_mfma_f32_16x16x32_bf16(a[1], b, acc[1][nb], 0, 0, 0);
        }
    }
    int rq = (lane >> 4) * 4;
#pragma unroll
    for (int m = 0; m < 2; m++) {
#pragma unroll
        for (int r = 0; r < 4; r++) {
            long row = rowbase + m * 16 + rq + r;
            if (row < NN) {
#pragma unroll
                for (int nb = 0; nb < 4; nb++)
                    y2[row * 64 + nb * 16 + lr] = f2b(acc[m][nb][r]);
            }
        }
    }
}

// ---------------- pull aggregation: one wave per node (100K waves -> TLP) ----------------

__global__ __launch_bounds__(256) void agg1_k(const ushort* __restrict__ y1,
                                              const int* __restrict__ nodeptr,
                                              const uint* __restrict__ col,
                                              const float* __restrict__ b1,
                                              ushort* __restrict__ h) {
    int wid = (blockIdx.x * 256 + threadIdx.x) >> 6;
    int lane = threadIdx.x & 63;
    if (wid >= NN) return;
    int s0 = nodeptr[wid], s1 = nodeptr[wid + 1];

    uint v = *(const uint*)(y1 + (size_t)wid * 128 + lane * 2);
    float a0 = bflo(v), a1 = bfhi(v);

    for (int i = s0; i < s1; i += 64) {
        int m = s1 - i;
        if (m > 64) m = 64;
        int sv = (lane < m) ? (int)col[i + lane] : 0;
        for (int j = 0; j < m; j++) {
            int sj = __shfl(sv, j);
            uint u = *(const uint*)(y1 + (size_t)sj * 128 + lane * 2);
            a0 += bflo(u);
            a1 += bfhi(u);
        }
    }
    a0 = fmaxf(a0 + b1[2 * lane], 0.f);
    a1 = fmaxf(a1 + b1[2 * lane + 1], 0.f);
    uint o = (uint)f2b(a0) | ((uint)f2b(a1) << 16);
    *(uint*)(h + (size_t)wid * 128 + lane * 2) = o;
}

__global__ __launch_bounds__(256) void agg2_k(const ushort* __restrict__ y2,
                                              const int* __restrict__ nodeptr,
                                              const uint* __restrict__ col,
                                              const float* __restrict__ b2,
                                              float* __restrict__ out) {
    int wid = (blockIdx.x * 256 + threadIdx.x) >> 6;
    int lane = threadIdx.x & 63;
    if (wid >= NN) return;
    int s0 = nodeptr[wid], s1 = nodeptr[wid + 1];

    float a = b2f(y2[(size_t)wid * 64 + lane]);

    for (int i = s0; i < s1; i += 64) {
        int m = s1 - i;
        if (m > 64) m = 64;
        int sv = (lane < m) ? (int)col[i + lane] : 0;
        for (int j = 0; j < m; j++) {
            int sj = __shfl(sv, j);
            a += b2f(y2[(size_t)sj * 64 + lane]);
        }
    }
    out[(size_t)wid * 64 + lane] = a + b2[lane];
}

// ---------------- launch ----------------

static constexpr size_t alup(size_t x) { return (x + 255) & ~(size_t)255; }
static constexpr size_t OFF_BCNT  = 0;
static constexpr size_t OFF_BBASE = alup(OFF_BCNT  + NBK * 4);
static constexpr size_t OFF_BCUR  = alup(OFF_BBASE + NBK * 4);
static constexpr size_t OFF_NPTR  = alup(OFF_BCUR  + NBK * 4);
static constexpr size_t OFF_BARR  = alup(OFF_NPTR  + (size_t)(NN + 1) * 4);
static constexpr size_t OFF_COL   = alup(OFF_BARR  + (size_t)NE * 4);
static constexpr size_t OFF_Y1    = alup(OFF_COL   + (size_t)NE * 4);
static constexpr size_t OFF_H     = alup(OFF_Y1 + (size_t)NN * 128 * 2);
static constexpr size_t OFF_Y2    = alup(OFF_H  + (size_t)NN * 128 * 2);

extern "C" void kernel_launch(void* const* d_in, const int* in_sizes, int n_in,
                              void* d_out, int out_size, void* d_ws, size_t ws_size,
                              hipStream_t stream) {
    const float* x  = (const float*)d_in[0];
    const int*   ei = (const int*)d_in[1];
    const float* W1 = (const float*)d_in[2];
    const float* b1 = (const float*)d_in[3];
    const float* W2 = (const float*)d_in[4];
    const float* b2 = (const float*)d_in[5];
    float* out = (float*)d_out;
    char* ws = (char*)d_ws;

    int*  bcnt  = (int*)(ws + OFF_BCNT);
    int*  bbase = (int*)(ws + OFF_BBASE);
    int*  bcur  = (int*)(ws + OFF_BCUR);
    int*  nptr  = (int*)(ws + OFF_NPTR);
    uint* barr  = (uint*)(ws + OFF_BARR);
    uint* colA  = (uint*)(ws + OFF_COL);
    ushort* y1 = (ushort*)(ws + OFF_Y1);
    ushort* hh = (ushort*)(ws + OFF_H);
    ushort* y2 = (ushort*)(ws + OFF_Y2);

    hipMemsetAsync(bcnt, 0, NBK * sizeof(int), stream);
    hipLaunchKernelGGL(bhist_k, dim3(256),  dim3(256),  0, stream, ei + NE, bcnt);
    hipLaunchKernelGGL(bscan_k, dim3(1),    dim3(1024), 0, stream, bcnt, bbase, bcur, nptr);
    hipLaunchKernelGGL(bfill_k, dim3(2048), dim3(256),  0, stream, ei, bcur, barr);
    hipLaunchKernelGGL(csr_k,   dim3(NBK),  dim3(256),  0, stream, barr, bbase, bcur, nptr, colA);

    hipLaunchKernelGGL(gemm1_k, dim3(782),  dim3(256), 0, stream, x, W1, y1);
    hipLaunchKernelGGL(agg1_k,  dim3(25000),dim3(256), 0, stream, y1, nptr, colA, b1, hh);
    hipLaunchKernelGGL(gemm2_k, dim3(782),  dim3(256), 0, stream, hh, W2, y2);
    hipLaunchKernelGGL(agg2_k,  dim3(25000),dim3(256), 0, stream, y2, nptr, colA, b2, out);
}

// Round 4
// 458.769 us; speedup vs baseline: 10.6713x; 2.5911x over previous
//
#include <hip/hip_runtime.h>
#include <stdint.h>

#define NN 100000
#define NE 3200000
#define NBK 782          // ceil(NN/128) buckets of 128 dst nodes
#define NB  256          // sort blocks
#define CH  12500        // edges per sort block: 256*12500 = 3.2M = NE

typedef unsigned int uint;
typedef unsigned short ushort;
typedef __attribute__((ext_vector_type(8))) short bf16x8;
typedef __attribute__((ext_vector_type(4))) float f32x4;

static __device__ __forceinline__ float bflo(uint v) {
    uint u = v << 16; return __builtin_bit_cast(float, u);
}
static __device__ __forceinline__ float bfhi(uint v) {
    uint u = v & 0xffff0000u; return __builtin_bit_cast(float, u);
}
static __device__ __forceinline__ float b2f(ushort v) {
    uint u = ((uint)v) << 16; return __builtin_bit_cast(float, u);
}
static __device__ __forceinline__ ushort f2b(float f) {  // RNE fp32->bf16
    uint u = __builtin_bit_cast(uint, f);
    u += 0x7fffu + ((u >> 16) & 1u);
    return (ushort)(u >> 16);
}
static __device__ __forceinline__ int wscan(int v, int lane) {  // 64-lane inclusive
#pragma unroll
    for (int off = 1; off < 64; off <<= 1) {
        int t = __shfl_up(v, off);
        if (lane >= off) v += t;
    }
    return v;
}

// ---------------- deterministic bucket counting-sort ----------------

// Pass 1: per-block histogram of its 12500-edge chunk over 782 buckets.
__global__ __launch_bounds__(512) void hist2_k(const int* __restrict__ ei,
                                               int* __restrict__ hist) {
    __shared__ int hl[NBK];
    int tid = threadIdx.x, b = blockIdx.x;
    for (int k = tid; k < NBK; k += 512) hl[k] = 0;
    __syncthreads();
    int base = b * CH;
    for (int i = base + tid; i < base + CH; i += 512)
        atomicAdd(&hl[ei[NE + i] >> 7], 1);
    __syncthreads();
    for (int k = tid; k < NBK; k += 512) hist[b * NBK + k] = hl[k];
}

// Pass 2a: per-bucket exclusive scan over blocks -> pbase[b][k], totals[k].
__global__ __launch_bounds__(64) void pbase_k(const int* __restrict__ hist,
                                              int* __restrict__ pbase,
                                              int* __restrict__ totals) {
    int k = blockIdx.x, lane = threadIdx.x;
    int carry = 0;
#pragma unroll
    for (int c = 0; c < NB / 64; ++c) {
        int b = c * 64 + lane;
        int v = hist[b * NBK + k];
        int incl = wscan(v, lane);
        pbase[b * NBK + k] = carry + incl - v;
        carry += __shfl(incl, 63);
    }
    if (lane == 0) totals[k] = carry;
}

// Pass 2b: scan bucket totals -> gbase (exclusive, with sentinel); nodeptr[NN]=NE.
__global__ __launch_bounds__(1024) void bscan_k(const int* __restrict__ totals,
                                                int* __restrict__ gbase,
                                                int* __restrict__ nodeptr) {
    __shared__ int sd[1024];
    int t = threadIdx.x;
    int v = (t < NBK) ? totals[t] : 0;
    sd[t] = v;
    __syncthreads();
    for (int off = 1; off < 1024; off <<= 1) {
        int u = (t >= off) ? sd[t - off] : 0;
        __syncthreads();
        sd[t] += u;
        __syncthreads();
    }
    int excl = sd[t] - v;
    if (t < NBK) gbase[t] = excl;
    if (t == 0) { gbase[NBK] = NE; nodeptr[NN] = NE; }
}

// Pass 3: LDS counting sort of each chunk, contiguous run copy-out. No global atomics.
__global__ __launch_bounds__(512) void bfill2_k(const int* __restrict__ ei,
                                                const int* __restrict__ pbase,
                                                const int* __restrict__ gbase,
                                                uint* __restrict__ barr) {
    __shared__ uint stg[CH];
    __shared__ int lstart[NBK + 1];
    __shared__ int cur[NBK];
    int tid = threadIdx.x, b = blockIdx.x;
    int base = b * CH;

    for (int k = tid; k < NBK; k += 512) cur[k] = 0;
    __syncthreads();
    for (int i = base + tid; i < base + CH; i += 512)
        atomicAdd(&cur[ei[NE + i] >> 7], 1);
    __syncthreads();
    if (tid < 64) {
        int carry = 0;
#pragma unroll
        for (int c = 0; c < 13; ++c) {
            int k = c * 64 + tid;
            int v = (k < NBK) ? cur[k] : 0;
            int incl = wscan(v, tid);
            if (k < NBK) lstart[k] = carry + incl - v;
            carry += __shfl(incl, 63);
        }
        if (tid == 0) lstart[NBK] = carry;   // == CH
    }
    __syncthreads();
    for (int k = tid; k < NBK; k += 512) cur[k] = lstart[k];
    __syncthreads();
    for (int i = base + tid; i < base + CH; i += 512) {
        int s = ei[i], d = ei[NE + i];
        int pos = atomicAdd(&cur[d >> 7], 1);       // LDS atomic only
        stg[pos] = ((uint)(d & 127) << 17) | (uint)s;
    }
    __syncthreads();
    for (int k = tid; k < NBK; k += 512)
        cur[k] = gbase[k] + pbase[b * NBK + k] - lstart[k];
    __syncthreads();
    for (int i = tid; i < CH; i += 512) {
        uint p = stg[i];
        int lo = 0, hi = NBK;                        // find bucket owning i
        while (hi - lo > 1) { int mid = (lo + hi) >> 1; if (lstart[mid] <= i) lo = mid; else hi = mid; }
        barr[cur[lo] + i] = p;                       // contiguous runs per bucket
    }
}

// within-bucket counting sort -> exact CSR (src-only) + nodeptr.
__global__ __launch_bounds__(256) void csr_k(const uint* __restrict__ barr,
                                             const int* __restrict__ gbase,
                                             int* __restrict__ nodeptr,
                                             uint* __restrict__ col) {
    __shared__ int cnt[128], cur[128];
    int tid = threadIdx.x;
    int blk = blockIdx.x;
    int s0 = gbase[blk], s1 = gbase[blk + 1];
    if (tid < 128) cnt[tid] = 0;
    __syncthreads();
    for (int i = s0 + tid; i < s1; i += 256)
        atomicAdd(&cnt[barr[i] >> 17], 1);
    __syncthreads();
    if (tid < 64) {
        int c0 = cnt[2 * tid], c1 = cnt[2 * tid + 1];
        int s = c0 + c1;
        int incl = s;
        for (int off = 1; off < 64; off <<= 1) {
            int t = __shfl_up(incl, off);
            if (tid >= off) incl += t;
        }
        int excl = incl - s;
        cur[2 * tid] = excl;
        cur[2 * tid + 1] = excl + c0;
        int node = blk * 128 + 2 * tid;
        if (node < NN)     nodeptr[node]     = s0 + excl;
        if (node + 1 < NN) nodeptr[node + 1] = s0 + excl + c0;
    }
    __syncthreads();
    for (int i = s0 + tid; i < s1; i += 256) {
        uint e = barr[i];
        int pos = s0 + atomicAdd(&cur[e >> 17], 1);
        col[pos] = e & 0x1FFFF;
    }
}

// ---------------- GEMM1: y1 = bf16( x @ W1^T ), x fp32 [NN,128] ----------------
__global__ __launch_bounds__(256) void gemm1_k(const float* __restrict__ x,
                                               const float* __restrict__ W1,
                                               ushort* __restrict__ y1) {
    __shared__ ushort wl[128 * 136];
    int tid = threadIdx.x;
    for (int i = tid; i < 128 * 128; i += 256)
        wl[(i >> 7) * 136 + (i & 127)] = f2b(W1[i]);
    __syncthreads();

    int wave = tid >> 6, lane = tid & 63;
    int lr = lane & 15, lk = (lane >> 4) * 8;
    long rowbase = (long)blockIdx.x * 128 + wave * 32;

    f32x4 acc[2][8] = {};
    for (int kc = 0; kc < 128; kc += 32) {
        bf16x8 a[2];
#pragma unroll
        for (int m = 0; m < 2; m++) {
            long row = rowbase + m * 16 + lr;
            if (row > NN - 1) row = NN - 1;
            const float* p = x + row * 128 + kc + lk;
            float f[8];
            *(float4*)(f)     = *(const float4*)(p);
            *(float4*)(f + 4) = *(const float4*)(p + 4);
            bf16x8 t;
#pragma unroll
            for (int j = 0; j < 8; j++) t[j] = (short)f2b(f[j]);
            a[m] = t;
        }
#pragma unroll
        for (int nb = 0; nb < 8; nb++) {
            bf16x8 b = *(const bf16x8*)&wl[(nb * 16 + lr) * 136 + kc + lk];
            acc[0][nb] = __builtin_amdgcn_mfma_f32_16x16x32_bf16(a[0], b, acc[0][nb], 0, 0, 0);
            acc[1][nb] = __builtin_amdgcn_mfma_f32_16x16x32_bf16(a[1], b, acc[1][nb], 0, 0, 0);
        }
    }
    int rq = (lane >> 4) * 4;
#pragma unroll
    for (int m = 0; m < 2; m++) {
#pragma unroll
        for (int r = 0; r < 4; r++) {
            long row = rowbase + m * 16 + rq + r;
            if (row < NN) {
#pragma unroll
                for (int nb = 0; nb < 8; nb++)
                    y1[row * 128 + nb * 16 + lr] = f2b(acc[m][nb][r]);
            }
        }
    }
}

// ---------------- GEMM2: y2 = bf16( h @ W2^T ), h bf16 [NN,128], W2 [64,128] ----------------
__global__ __launch_bounds__(256) void gemm2_k(const ushort* __restrict__ h,
                                               const float* __restrict__ W2,
                                               ushort* __restrict__ y2) {
    __shared__ ushort wl[64 * 136];
    int tid = threadIdx.x;
    for (int i = tid; i < 64 * 128; i += 256)
        wl[(i >> 7) * 136 + (i & 127)] = f2b(W2[i]);
    __syncthreads();

    int wave = tid >> 6, lane = tid & 63;
    int lr = lane & 15, lk = (lane >> 4) * 8;
    long rowbase = (long)blockIdx.x * 128 + wave * 32;

    f32x4 acc[2][4] = {};
    for (int kc = 0; kc < 128; kc += 32) {
        bf16x8 a[2];
#pragma unroll
        for (int m = 0; m < 2; m++) {
            long row = rowbase + m * 16 + lr;
            if (row > NN - 1) row = NN - 1;
            a[m] = *(const bf16x8*)(h + row * 128 + kc + lk);
        }
#pragma unroll
        for (int nb = 0; nb < 4; nb++) {
            bf16x8 b = *(const bf16x8*)&wl[(nb * 16 + lr) * 136 + kc + lk];
            acc[0][nb] = __builtin_amdgcn_mfma_f32_16x16x32_bf16(a[0], b, acc[0][nb], 0, 0, 0);
            acc[1][nb] = __builtin_amdgcn_mfma_f32_16x16x32_bf16(a[1], b, acc[1][nb], 0, 0, 0);
        }
    }
    int rq = (lane >> 4) * 4;
#pragma unroll
    for (int m = 0; m < 2; m++) {
#pragma unroll
        for (int r = 0; r < 4; r++) {
            long row = rowbase + m * 16 + rq + r;
            if (row < NN) {
#pragma unroll
                for (int nb = 0; nb < 4; nb++)
                    y2[row * 64 + nb * 16 + lr] = f2b(acc[m][nb][r]);
            }
        }
    }
}

// ---------------- pull aggregation: one wave per node ----------------

__global__ __launch_bounds__(256) void agg1_k(const ushort* __restrict__ y1,
                                              const int* __restrict__ nodeptr,
                                              const uint* __restrict__ col,
                                              const float* __restrict__ b1,
                                              ushort* __restrict__ h) {
    int wid = (blockIdx.x * 256 + threadIdx.x) >> 6;
    int lane = threadIdx.x & 63;
    if (wid >= NN) return;
    int s0 = nodeptr[wid], s1 = nodeptr[wid + 1];

    uint v = *(const uint*)(y1 + (size_t)wid * 128 + lane * 2);
    float a0 = bflo(v), a1 = bfhi(v);

    for (int i = s0; i < s1; i += 64) {
        int m = s1 - i;
        if (m > 64) m = 64;
        int sv = (lane < m) ? (int)col[i + lane] : 0;
        for (int j = 0; j < m; j++) {
            int sj = __shfl(sv, j);
            uint u = *(const uint*)(y1 + (size_t)sj * 128 + lane * 2);
            a0 += bflo(u);
            a1 += bfhi(u);
        }
    }
    a0 = fmaxf(a0 + b1[2 * lane], 0.f);
    a1 = fmaxf(a1 + b1[2 * lane + 1], 0.f);
    uint o = (uint)f2b(a0) | ((uint)f2b(a1) << 16);
    *(uint*)(h + (size_t)wid * 128 + lane * 2) = o;
}

__global__ __launch_bounds__(256) void agg2_k(const ushort* __restrict__ y2,
                                              const int* __restrict__ nodeptr,
                                              const uint* __restrict__ col,
                                              const float* __restrict__ b2,
                                              float* __restrict__ out) {
    int wid = (blockIdx.x * 256 + threadIdx.x) >> 6;
    int lane = threadIdx.x & 63;
    if (wid >= NN) return;
    int s0 = nodeptr[wid], s1 = nodeptr[wid + 1];

    float a = b2f(y2[(size_t)wid * 64 + lane]);

    for (int i = s0; i < s1; i += 64) {
        int m = s1 - i;
        if (m > 64) m = 64;
        int sv = (lane < m) ? (int)col[i + lane] : 0;
        for (int j = 0; j < m; j++) {
            int sj = __shfl(sv, j);
            a += b2f(y2[(size_t)sj * 64 + lane]);
        }
    }
    out[(size_t)wid * 64 + lane] = a + b2[lane];
}

// ---------------- launch ----------------

static constexpr size_t alup(size_t x) { return (x + 255) & ~(size_t)255; }
static constexpr size_t OFF_HIST  = 0;
static constexpr size_t OFF_PBASE = alup(OFF_HIST  + (size_t)NB * NBK * 4);
static constexpr size_t OFF_TOT   = alup(OFF_PBASE + (size_t)NB * NBK * 4);
static constexpr size_t OFF_GBASE = alup(OFF_TOT   + NBK * 4);
static constexpr size_t OFF_NPTR  = alup(OFF_GBASE + (NBK + 1) * 4);
static constexpr size_t OFF_BARR  = alup(OFF_NPTR  + (size_t)(NN + 1) * 4);
static constexpr size_t OFF_COL   = alup(OFF_BARR  + (size_t)NE * 4);
static constexpr size_t OFF_Y1    = alup(OFF_COL   + (size_t)NE * 4);
static constexpr size_t OFF_H     = alup(OFF_Y1 + (size_t)NN * 128 * 2);
static constexpr size_t OFF_Y2    = alup(OFF_H  + (size_t)NN * 128 * 2);

extern "C" void kernel_launch(void* const* d_in, const int* in_sizes, int n_in,
                              void* d_out, int out_size, void* d_ws, size_t ws_size,
                              hipStream_t stream) {
    const float* x  = (const float*)d_in[0];
    const int*   ei = (const int*)d_in[1];
    const float* W1 = (const float*)d_in[2];
    const float* b1 = (const float*)d_in[3];
    const float* W2 = (const float*)d_in[4];
    const float* b2 = (const float*)d_in[5];
    float* out = (float*)d_out;
    char* ws = (char*)d_ws;

    int*  hist  = (int*)(ws + OFF_HIST);
    int*  pbase = (int*)(ws + OFF_PBASE);
    int*  tot   = (int*)(ws + OFF_TOT);
    int*  gbase = (int*)(ws + OFF_GBASE);
    int*  nptr  = (int*)(ws + OFF_NPTR);
    uint* barr  = (uint*)(ws + OFF_BARR);
    uint* colA  = (uint*)(ws + OFF_COL);
    ushort* y1 = (ushort*)(ws + OFF_Y1);
    ushort* hh = (ushort*)(ws + OFF_H);
    ushort* y2 = (ushort*)(ws + OFF_Y2);

    hipLaunchKernelGGL(hist2_k,  dim3(NB),  dim3(512),  0, stream, ei, hist);
    hipLaunchKernelGGL(pbase_k,  dim3(NBK), dim3(64),   0, stream, hist, pbase, tot);
    hipLaunchKernelGGL(bscan_k,  dim3(1),   dim3(1024), 0, stream, tot, gbase, nptr);
    hipLaunchKernelGGL(bfill2_k, dim3(NB),  dim3(512),  0, stream, ei, pbase, gbase, barr);
    hipLaunchKernelGGL(csr_k,    dim3(NBK), dim3(256),  0, stream, barr, gbase, nptr, colA);

    hipLaunchKernelGGL(gemm1_k, dim3(782),  dim3(256), 0, stream, x, W1, y1);
    hipLaunchKernelGGL(agg1_k,  dim3(25000),dim3(256), 0, stream, y1, nptr, colA, b1, hh);
    hipLaunchKernelGGL(gemm2_k, dim3(782),  dim3(256), 0, stream, hh, W2, y2);
    hipLaunchKernelGGL(agg2_k,  dim3(25000),dim3(256), 0, stream, y2, nptr, colA, b2, out);
}

// Round 5
// 286.572 us; speedup vs baseline: 17.0835x; 1.6009x over previous
//
#include <hip/hip_runtime.h>
#include <stdint.h>

#define NN 100000
#define NE 3200000
#define NBK 782          // ceil(NN/128) buckets of 128 dst nodes
#define NB  256          // sort blocks
#define CH  12500        // edges per sort block: 256*12500 = 3.2M = NE

typedef unsigned int uint;
typedef unsigned short ushort;
typedef __attribute__((ext_vector_type(8))) short bf16x8;
typedef __attribute__((ext_vector_type(4))) float f32x4;

static __device__ __forceinline__ float bflo(uint v) {
    uint u = v << 16; return __builtin_bit_cast(float, u);
}
static __device__ __forceinline__ float bfhi(uint v) {
    uint u = v & 0xffff0000u; return __builtin_bit_cast(float, u);
}
static __device__ __forceinline__ float b2f(ushort v) {
    uint u = ((uint)v) << 16; return __builtin_bit_cast(float, u);
}
static __device__ __forceinline__ ushort f2b(float f) {  // RNE fp32->bf16
    uint u = __builtin_bit_cast(uint, f);
    u += 0x7fffu + ((u >> 16) & 1u);
    return (ushort)(u >> 16);
}
static __device__ __forceinline__ int wscan(int v, int lane) {  // 64-lane inclusive
#pragma unroll
    for (int off = 1; off < 64; off <<= 1) {
        int t = __shfl_up(v, off);
        if (lane >= off) v += t;
    }
    return v;
}

// ---------------- deterministic bucket counting-sort ----------------

__global__ __launch_bounds__(512) void hist2_k(const int* __restrict__ ei,
                                               int* __restrict__ hist) {
    __shared__ int hl[NBK];
    int tid = threadIdx.x, b = blockIdx.x;
    for (int k = tid; k < NBK; k += 512) hl[k] = 0;
    __syncthreads();
    int base = b * CH;
    for (int i = base + tid; i < base + CH; i += 512)
        atomicAdd(&hl[ei[NE + i] >> 7], 1);
    __syncthreads();
    for (int k = tid; k < NBK; k += 512) hist[b * NBK + k] = hl[k];
}

__global__ __launch_bounds__(64) void pbase_k(const int* __restrict__ hist,
                                              int* __restrict__ pbase,
                                              int* __restrict__ totals) {
    int k = blockIdx.x, lane = threadIdx.x;
    int carry = 0;
#pragma unroll
    for (int c = 0; c < NB / 64; ++c) {
        int b = c * 64 + lane;
        int v = hist[b * NBK + k];
        int incl = wscan(v, lane);
        pbase[b * NBK + k] = carry + incl - v;
        carry += __shfl(incl, 63);
    }
    if (lane == 0) totals[k] = carry;
}

__global__ __launch_bounds__(1024) void bscan_k(const int* __restrict__ totals,
                                                int* __restrict__ gbase,
                                                int* __restrict__ nodeptr) {
    __shared__ int sd[1024];
    int t = threadIdx.x;
    int v = (t < NBK) ? totals[t] : 0;
    sd[t] = v;
    __syncthreads();
    for (int off = 1; off < 1024; off <<= 1) {
        int u = (t >= off) ? sd[t - off] : 0;
        __syncthreads();
        sd[t] += u;
        __syncthreads();
    }
    int excl = sd[t] - v;
    if (t < NBK) gbase[t] = excl;
    if (t == 0) { gbase[NBK] = NE; nodeptr[NN] = NE; }
}

__global__ __launch_bounds__(512) void bfill2_k(const int* __restrict__ ei,
                                                const int* __restrict__ pbase,
                                                const int* __restrict__ gbase,
                                                uint* __restrict__ barr) {
    __shared__ uint stg[CH];
    __shared__ int lstart[NBK + 1];
    __shared__ int cur[NBK];
    int tid = threadIdx.x, b = blockIdx.x;
    int base = b * CH;

    for (int k = tid; k < NBK; k += 512) cur[k] = 0;
    __syncthreads();
    for (int i = base + tid; i < base + CH; i += 512)
        atomicAdd(&cur[ei[NE + i] >> 7], 1);
    __syncthreads();
    if (tid < 64) {
        int carry = 0;
#pragma unroll
        for (int c = 0; c < 13; ++c) {
            int k = c * 64 + tid;
            int v = (k < NBK) ? cur[k] : 0;
            int incl = wscan(v, tid);
            if (k < NBK) lstart[k] = carry + incl - v;
            carry += __shfl(incl, 63);
        }
        if (tid == 0) lstart[NBK] = carry;   // == CH
    }
    __syncthreads();
    for (int k = tid; k < NBK; k += 512) cur[k] = lstart[k];
    __syncthreads();
    for (int i = base + tid; i < base + CH; i += 512) {
        int s = ei[i], d = ei[NE + i];
        int pos = atomicAdd(&cur[d >> 7], 1);       // LDS atomic only
        stg[pos] = ((uint)(d & 127) << 17) | (uint)s;
    }
    __syncthreads();
    for (int k = tid; k < NBK; k += 512)
        cur[k] = gbase[k] + pbase[b * NBK + k] - lstart[k];
    __syncthreads();
    for (int i = tid; i < CH; i += 512) {
        uint p = stg[i];
        int lo = 0, hi = NBK;
        while (hi - lo > 1) { int mid = (lo + hi) >> 1; if (lstart[mid] <= i) lo = mid; else hi = mid; }
        barr[cur[lo] + i] = p;
    }
}

__global__ __launch_bounds__(256) void csr_k(const uint* __restrict__ barr,
                                             const int* __restrict__ gbase,
                                             int* __restrict__ nodeptr,
                                             uint* __restrict__ col) {
    __shared__ int cnt[128], cur[128];
    int tid = threadIdx.x;
    int blk = blockIdx.x;
    int s0 = gbase[blk], s1 = gbase[blk + 1];
    if (tid < 128) cnt[tid] = 0;
    __syncthreads();
    for (int i = s0 + tid; i < s1; i += 256)
        atomicAdd(&cnt[barr[i] >> 17], 1);
    __syncthreads();
    if (tid < 64) {
        int c0 = cnt[2 * tid], c1 = cnt[2 * tid + 1];
        int s = c0 + c1;
        int incl = s;
        for (int off = 1; off < 64; off <<= 1) {
            int t = __shfl_up(incl, off);
            if (tid >= off) incl += t;
        }
        int excl = incl - s;
        cur[2 * tid] = excl;
        cur[2 * tid + 1] = excl + c0;
        int node = blk * 128 + 2 * tid;
        if (node < NN)     nodeptr[node]     = s0 + excl;
        if (node + 1 < NN) nodeptr[node + 1] = s0 + excl + c0;
    }
    __syncthreads();
    for (int i = s0 + tid; i < s1; i += 256) {
        uint e = barr[i];
        int pos = s0 + atomicAdd(&cur[e >> 17], 1);
        col[pos] = e & 0x1FFFF;
    }
}

// ---------------- GEMM1: y1 = bf16( x @ W1^T ), x fp32 [NN,128] ----------------
__global__ __launch_bounds__(256) void gemm1_k(const float* __restrict__ x,
                                               const float* __restrict__ W1,
                                               ushort* __restrict__ y1) {
    __shared__ ushort wl[128 * 136];
    int tid = threadIdx.x;
    for (int i = tid; i < 128 * 128; i += 256)
        wl[(i >> 7) * 136 + (i & 127)] = f2b(W1[i]);
    __syncthreads();

    int wave = tid >> 6, lane = tid & 63;
    int lr = lane & 15, lk = (lane >> 4) * 8;
    long rowbase = (long)blockIdx.x * 128 + wave * 32;

    f32x4 acc[2][8] = {};
    for (int kc = 0; kc < 128; kc += 32) {
        bf16x8 a[2];
#pragma unroll
        for (int m = 0; m < 2; m++) {
            long row = rowbase + m * 16 + lr;
            if (row > NN - 1) row = NN - 1;
            const float* p = x + row * 128 + kc + lk;
            float f[8];
            *(float4*)(f)     = *(const float4*)(p);
            *(float4*)(f + 4) = *(const float4*)(p + 4);
            bf16x8 t;
#pragma unroll
            for (int j = 0; j < 8; j++) t[j] = (short)f2b(f[j]);
            a[m] = t;
        }
#pragma unroll
        for (int nb = 0; nb < 8; nb++) {
            bf16x8 b = *(const bf16x8*)&wl[(nb * 16 + lr) * 136 + kc + lk];
            acc[0][nb] = __builtin_amdgcn_mfma_f32_16x16x32_bf16(a[0], b, acc[0][nb], 0, 0, 0);
            acc[1][nb] = __builtin_amdgcn_mfma_f32_16x16x32_bf16(a[1], b, acc[1][nb], 0, 0, 0);
        }
    }
    int rq = (lane >> 4) * 4;
#pragma unroll
    for (int m = 0; m < 2; m++) {
#pragma unroll
        for (int r = 0; r < 4; r++) {
            long row = rowbase + m * 16 + rq + r;
            if (row < NN) {
#pragma unroll
                for (int nb = 0; nb < 8; nb++)
                    y1[row * 128 + nb * 16 + lr] = f2b(acc[m][nb][r]);
            }
        }
    }
}

// ---------------- GEMM2: y2 = bf16( h @ W2^T ), h bf16 [NN,128], W2 [64,128] ----------------
__global__ __launch_bounds__(256) void gemm2_k(const ushort* __restrict__ h,
                                               const float* __restrict__ W2,
                                               ushort* __restrict__ y2) {
    __shared__ ushort wl[64 * 136];
    int tid = threadIdx.x;
    for (int i = tid; i < 64 * 128; i += 256)
        wl[(i >> 7) * 136 + (i & 127)] = f2b(W2[i]);
    __syncthreads();

    int wave = tid >> 6, lane = tid & 63;
    int lr = lane & 15, lk = (lane >> 4) * 8;
    long rowbase = (long)blockIdx.x * 128 + wave * 32;

    f32x4 acc[2][4] = {};
    for (int kc = 0; kc < 128; kc += 32) {
        bf16x8 a[2];
#pragma unroll
        for (int m = 0; m < 2; m++) {
            long row = rowbase + m * 16 + lr;
            if (row > NN - 1) row = NN - 1;
            a[m] = *(const bf16x8*)(h + row * 128 + kc + lk);
        }
#pragma unroll
        for (int nb = 0; nb < 4; nb++) {
            bf16x8 b = *(const bf16x8*)&wl[(nb * 16 + lr) * 136 + kc + lk];
            acc[0][nb] = __builtin_amdgcn_mfma_f32_16x16x32_bf16(a[0], b, acc[0][nb], 0, 0, 0);
            acc[1][nb] = __builtin_amdgcn_mfma_f32_16x16x32_bf16(a[1], b, acc[1][nb], 0, 0, 0);
        }
    }
    int rq = (lane >> 4) * 4;
#pragma unroll
    for (int m = 0; m < 2; m++) {
#pragma unroll
        for (int r = 0; r < 4; r++) {
            long row = rowbase + m * 16 + rq + r;
            if (row < NN) {
#pragma unroll
                for (int nb = 0; nb < 4; nb++)
                    y2[row * 64 + nb * 16 + lr] = f2b(acc[m][nb][r]);
            }
        }
    }
}

// ---------------- pull aggregation: wave per node, quarter-wave per edge ----------------
// Lane r=lane&15 owns 8 dims (16B); quarter q=lane>>4 processes edge 4j+q.
// One variable-lane __shfl dispatches 4 edges; dwordx4 gathers give 4x MLP.

__global__ __launch_bounds__(256) void agg1_k(const ushort* __restrict__ y1,
                                              const int* __restrict__ nodeptr,
                                              const uint* __restrict__ col,
                                              const float* __restrict__ b1,
                                              ushort* __restrict__ h) {
    int wid = (blockIdx.x * 256 + threadIdx.x) >> 6;
    int lane = threadIdx.x & 63;
    if (wid >= NN) return;
    int s0 = nodeptr[wid], s1 = nodeptr[wid + 1];
    int q = lane >> 4, r = lane & 15;

    float acc[8] = {};

    for (int i = s0; i < s1; i += 64) {
        int m = s1 - i; if (m > 64) m = 64;
        int sv = (lane < m) ? (int)col[i + lane] : 0;
        int jmax = (m + 3) >> 2;
        for (int j = 0; j < jmax; ++j) {
            int eid = 4 * j + q;
            int sj = __shfl(sv, eid);
            uint4 u = *(const uint4*)(y1 + (size_t)sj * 128 + r * 8);
            if (eid < m) {
                acc[0] += bflo(u.x); acc[1] += bfhi(u.x);
                acc[2] += bflo(u.y); acc[3] += bfhi(u.y);
                acc[4] += bflo(u.z); acc[5] += bfhi(u.z);
                acc[6] += bflo(u.w); acc[7] += bfhi(u.w);
            }
        }
    }
#pragma unroll
    for (int d = 0; d < 8; ++d) {
        acc[d] += __shfl_xor(acc[d], 16);
        acc[d] += __shfl_xor(acc[d], 32);
    }
    if (q == 0) {
        uint4 s = *(const uint4*)(y1 + (size_t)wid * 128 + r * 8);
        float4 bA = *(const float4*)(b1 + r * 8);
        float4 bB = *(const float4*)(b1 + r * 8 + 4);
        float v0 = fmaxf(acc[0] + bflo(s.x) + bA.x, 0.f);
        float v1 = fmaxf(acc[1] + bfhi(s.x) + bA.y, 0.f);
        float v2 = fmaxf(acc[2] + bflo(s.y) + bA.z, 0.f);
        float v3 = fmaxf(acc[3] + bfhi(s.y) + bA.w, 0.f);
        float v4 = fmaxf(acc[4] + bflo(s.z) + bB.x, 0.f);
        float v5 = fmaxf(acc[5] + bfhi(s.z) + bB.y, 0.f);
        float v6 = fmaxf(acc[6] + bflo(s.w) + bB.z, 0.f);
        float v7 = fmaxf(acc[7] + bfhi(s.w) + bB.w, 0.f);
        uint4 o;
        o.x = (uint)f2b(v0) | ((uint)f2b(v1) << 16);
        o.y = (uint)f2b(v2) | ((uint)f2b(v3) << 16);
        o.z = (uint)f2b(v4) | ((uint)f2b(v5) << 16);
        o.w = (uint)f2b(v6) | ((uint)f2b(v7) << 16);
        *(uint4*)(h + (size_t)wid * 128 + r * 8) = o;
    }
}

// Layer 2: D=64, lane owns 4 dims (8B), quarter-wave per edge, dwordx2 gathers.
__global__ __launch_bounds__(256) void agg2_k(const ushort* __restrict__ y2,
                                              const int* __restrict__ nodeptr,
                                              const uint* __restrict__ col,
                                              const float* __restrict__ b2,
                                              float* __restrict__ out) {
    int wid = (blockIdx.x * 256 + threadIdx.x) >> 6;
    int lane = threadIdx.x & 63;
    if (wid >= NN) return;
    int s0 = nodeptr[wid], s1 = nodeptr[wid + 1];
    int q = lane >> 4, r = lane & 15;

    float acc[4] = {};

    for (int i = s0; i < s1; i += 64) {
        int m = s1 - i; if (m > 64) m = 64;
        int sv = (lane < m) ? (int)col[i + lane] : 0;
        int jmax = (m + 3) >> 2;
        for (int j = 0; j < jmax; ++j) {
            int eid = 4 * j + q;
            int sj = __shfl(sv, eid);
            uint2 u = *(const uint2*)(y2 + (size_t)sj * 64 + r * 4);
            if (eid < m) {
                acc[0] += bflo(u.x); acc[1] += bfhi(u.x);
                acc[2] += bflo(u.y); acc[3] += bfhi(u.y);
            }
        }
    }
#pragma unroll
    for (int d = 0; d < 4; ++d) {
        acc[d] += __shfl_xor(acc[d], 16);
        acc[d] += __shfl_xor(acc[d], 32);
    }
    if (q == 0) {
        uint2 s = *(const uint2*)(y2 + (size_t)wid * 64 + r * 4);
        float4 bb = *(const float4*)(b2 + r * 4);
        float4 o;
        o.x = acc[0] + bflo(s.x) + bb.x;
        o.y = acc[1] + bfhi(s.x) + bb.y;
        o.z = acc[2] + bflo(s.y) + bb.z;
        o.w = acc[3] + bfhi(s.y) + bb.w;
        *(float4*)(out + (size_t)wid * 64 + r * 4) = o;
    }
}

// ---------------- launch ----------------

static constexpr size_t alup(size_t x) { return (x + 255) & ~(size_t)255; }
static constexpr size_t OFF_HIST  = 0;
static constexpr size_t OFF_PBASE = alup(OFF_HIST  + (size_t)NB * NBK * 4);
static constexpr size_t OFF_TOT   = alup(OFF_PBASE + (size_t)NB * NBK * 4);
static constexpr size_t OFF_GBASE = alup(OFF_TOT   + NBK * 4);
static constexpr size_t OFF_NPTR  = alup(OFF_GBASE + (NBK + 1) * 4);
static constexpr size_t OFF_BARR  = alup(OFF_NPTR  + (size_t)(NN + 1) * 4);
static constexpr size_t OFF_COL   = alup(OFF_BARR  + (size_t)NE * 4);
static constexpr size_t OFF_Y1    = alup(OFF_COL   + (size_t)NE * 4);
static constexpr size_t OFF_H     = alup(OFF_Y1 + (size_t)NN * 128 * 2);
static constexpr size_t OFF_Y2    = alup(OFF_H  + (size_t)NN * 128 * 2);

extern "C" void kernel_launch(void* const* d_in, const int* in_sizes, int n_in,
                              void* d_out, int out_size, void* d_ws, size_t ws_size,
                              hipStream_t stream) {
    const float* x  = (const float*)d_in[0];
    const int*   ei = (const int*)d_in[1];
    const float* W1 = (const float*)d_in[2];
    const float* b1 = (const float*)d_in[3];
    const float* W2 = (const float*)d_in[4];
    const float* b2 = (const float*)d_in[5];
    float* out = (float*)d_out;
    char* ws = (char*)d_ws;

    int*  hist  = (int*)(ws + OFF_HIST);
    int*  pbase = (int*)(ws + OFF_PBASE);
    int*  tot   = (int*)(ws + OFF_TOT);
    int*  gbase = (int*)(ws + OFF_GBASE);
    int*  nptr  = (int*)(ws + OFF_NPTR);
    uint* barr  = (uint*)(ws + OFF_BARR);
    uint* colA  = (uint*)(ws + OFF_COL);
    ushort* y1 = (ushort*)(ws + OFF_Y1);
    ushort* hh = (ushort*)(ws + OFF_H);
    ushort* y2 = (ushort*)(ws + OFF_Y2);

    hipLaunchKernelGGL(hist2_k,  dim3(NB),  dim3(512),  0, stream, ei, hist);
    hipLaunchKernelGGL(pbase_k,  dim3(NBK), dim3(64),   0, stream, hist, pbase, tot);
    hipLaunchKernelGGL(bscan_k,  dim3(1),   dim3(1024), 0, stream, tot, gbase, nptr);
    hipLaunchKernelGGL(bfill2_k, dim3(NB),  dim3(512),  0, stream, ei, pbase, gbase, barr);
    hipLaunchKernelGGL(csr_k,    dim3(NBK), dim3(256),  0, stream, barr, gbase, nptr, colA);

    hipLaunchKernelGGL(gemm1_k, dim3(782),  dim3(256), 0, stream, x, W1, y1);
    hipLaunchKernelGGL(agg1_k,  dim3(25000),dim3(256), 0, stream, y1, nptr, colA, b1, hh);
    hipLaunchKernelGGL(gemm2_k, dim3(782),  dim3(256), 0, stream, hh, W2, y2);
    hipLaunchKernelGGL(agg2_k,  dim3(25000),dim3(256), 0, stream, y2, nptr, colA, b2, out);
}

// Round 6
// 284.086 us; speedup vs baseline: 17.2330x; 1.0088x over previous
//
#include <hip/hip_runtime.h>
#include <stdint.h>

#define NN 100000
#define NE 3200000
#define NBK 782          // ceil(NN/128) buckets of 128 dst nodes
#define NB  512          // sort blocks
#define CH  6250         // edges per sort block: 512*6250 = 3.2M = NE
#define CSRCAP 4800      // LDS staging capacity per bucket (mean 4096, 5-sigma ~4420)

typedef unsigned int uint;
typedef unsigned short ushort;
typedef __attribute__((ext_vector_type(8))) short bf16x8;
typedef __attribute__((ext_vector_type(4))) float f32x4;

static __device__ __forceinline__ float bflo(uint v) {
    uint u = v << 16; return __builtin_bit_cast(float, u);
}
static __device__ __forceinline__ float bfhi(uint v) {
    uint u = v & 0xffff0000u; return __builtin_bit_cast(float, u);
}
static __device__ __forceinline__ float bfraw(uint v) {   // hi bf16 with low-bit junk (<=2^-8 rel)
    return __builtin_bit_cast(float, v);
}
static __device__ __forceinline__ float b2f(ushort v) {
    uint u = ((uint)v) << 16; return __builtin_bit_cast(float, u);
}
static __device__ __forceinline__ ushort f2b(float f) {  // RNE fp32->bf16
    uint u = __builtin_bit_cast(uint, f);
    u += 0x7fffu + ((u >> 16) & 1u);
    return (ushort)(u >> 16);
}
static __device__ __forceinline__ int wscan(int v, int lane) {  // 64-lane inclusive
#pragma unroll
    for (int off = 1; off < 64; off <<= 1) {
        int t = __shfl_up(v, off);
        if (lane >= off) v += t;
    }
    return v;
}

// ---------------- deterministic bucket counting-sort ----------------

__global__ __launch_bounds__(512) void hist2_k(const int* __restrict__ ei,
                                               int* __restrict__ hist) {
    __shared__ int hl[NBK];
    int tid = threadIdx.x, b = blockIdx.x;
    for (int k = tid; k < NBK; k += 512) hl[k] = 0;
    __syncthreads();
    int base = b * CH;
    for (int i = base + tid; i < base + CH; i += 512)
        atomicAdd(&hl[ei[NE + i] >> 7], 1);
    __syncthreads();
    for (int k = tid; k < NBK; k += 512) hist[b * NBK + k] = hl[k];
}

__global__ __launch_bounds__(64) void pbase_k(const int* __restrict__ hist,
                                              int* __restrict__ pbase,
                                              int* __restrict__ totals) {
    int k = blockIdx.x, lane = threadIdx.x;
    int carry = 0;
#pragma unroll
    for (int c = 0; c < NB / 64; ++c) {
        int b = c * 64 + lane;
        int v = hist[b * NBK + k];
        int incl = wscan(v, lane);
        pbase[b * NBK + k] = carry + incl - v;
        carry += __shfl(incl, 63);
    }
    if (lane == 0) totals[k] = carry;
}

// scan bucket totals -> gbase; also zero the pad rows (index NN) of y1/y2.
__global__ __launch_bounds__(1024) void bscan_k(const int* __restrict__ totals,
                                                int* __restrict__ gbase,
                                                int* __restrict__ nodeptr,
                                                ushort* __restrict__ y1,
                                                ushort* __restrict__ y2) {
    __shared__ int sd[1024];
    int t = threadIdx.x;
    int v = (t < NBK) ? totals[t] : 0;
    sd[t] = v;
    __syncthreads();
    for (int off = 1; off < 1024; off <<= 1) {
        int u = (t >= off) ? sd[t - off] : 0;
        __syncthreads();
        sd[t] += u;
        __syncthreads();
    }
    int excl = sd[t] - v;
    if (t < NBK) gbase[t] = excl;
    if (t == 0) { gbase[NBK] = NE; nodeptr[NN] = NE; }
    if (t < 64) ((uint*)(y1 + (size_t)NN * 128))[t] = 0;   // zero pad row (256B)
    if (t < 32) ((uint*)(y2 + (size_t)NN * 64))[t] = 0;    // zero pad row (128B)
}

// direct scatter with LDS cursors seeded from gbase+pbase. No staging, no search.
__global__ __launch_bounds__(512) void bfill2_k(const int* __restrict__ ei,
                                                const int* __restrict__ pbase,
                                                const int* __restrict__ gbase,
                                                uint* __restrict__ barr) {
    __shared__ int cur[NBK];
    int tid = threadIdx.x, b = blockIdx.x;
    for (int k = tid; k < NBK; k += 512)
        cur[k] = gbase[k] + pbase[b * NBK + k];
    __syncthreads();
    int base = b * CH;
    for (int i = base + tid; i < base + CH; i += 512) {
        int s = ei[i], d = ei[NE + i];
        int pos = atomicAdd(&cur[d >> 7], 1);       // LDS atomic only
        barr[pos] = ((uint)(d & 127) << 17) | (uint)s;
    }
}

// within-bucket counting sort via LDS staging (single global read of the bucket).
__global__ __launch_bounds__(256) void csr_k(const uint* __restrict__ barr,
                                             const int* __restrict__ gbase,
                                             int* __restrict__ nodeptr,
                                             uint* __restrict__ col) {
    __shared__ uint stg[CSRCAP];
    __shared__ int cnt[128], cur[128];
    int tid = threadIdx.x;
    int blk = blockIdx.x;
    int s0 = gbase[blk], s1 = gbase[blk + 1];
    int n = s1 - s0;
    bool fits = (n <= CSRCAP);
    if (tid < 128) cnt[tid] = 0;
    __syncthreads();
    if (fits) {
        for (int i = tid; i < n; i += 256) {
            uint e = barr[s0 + i];
            stg[i] = e;
            atomicAdd(&cnt[e >> 17], 1);
        }
    } else {
        for (int i = s0 + tid; i < s1; i += 256)
            atomicAdd(&cnt[barr[i] >> 17], 1);
    }
    __syncthreads();
    if (tid < 64) {
        int c0 = cnt[2 * tid], c1 = cnt[2 * tid + 1];
        int s = c0 + c1;
        int incl = wscan(s, tid);
        int excl = incl - s;
        cur[2 * tid] = excl;
        cur[2 * tid + 1] = excl + c0;
        int node = blk * 128 + 2 * tid;
        if (node < NN)     nodeptr[node]     = s0 + excl;
        if (node + 1 < NN) nodeptr[node + 1] = s0 + excl + c0;
    }
    __syncthreads();
    if (fits) {
        for (int i = tid; i < n; i += 256) {
            uint e = stg[i];
            int pos = s0 + atomicAdd(&cur[e >> 17], 1);
            col[pos] = e & 0x1FFFF;
        }
    } else {
        for (int i = s0 + tid; i < s1; i += 256) {
            uint e = barr[i];
            int pos = s0 + atomicAdd(&cur[e >> 17], 1);
            col[pos] = e & 0x1FFFF;
        }
    }
}

// ---------------- GEMM1: y1 = bf16( x @ W1^T ), x fp32 [NN,128] ----------------
__global__ __launch_bounds__(256) void gemm1_k(const float* __restrict__ x,
                                               const float* __restrict__ W1,
                                               ushort* __restrict__ y1) {
    __shared__ ushort wl[128 * 136];
    int tid = threadIdx.x;
    for (int i = tid; i < 128 * 128; i += 256)
        wl[(i >> 7) * 136 + (i & 127)] = f2b(W1[i]);
    __syncthreads();

    int wave = tid >> 6, lane = tid & 63;
    int lr = lane & 15, lk = (lane >> 4) * 8;
    long rowbase = (long)blockIdx.x * 128 + wave * 32;

    f32x4 acc[2][8] = {};
    for (int kc = 0; kc < 128; kc += 32) {
        bf16x8 a[2];
#pragma unroll
        for (int m = 0; m < 2; m++) {
            long row = rowbase + m * 16 + lr;
            if (row > NN - 1) row = NN - 1;
            const float* p = x + row * 128 + kc + lk;
            float f[8];
            *(float4*)(f)     = *(const float4*)(p);
            *(float4*)(f + 4) = *(const float4*)(p + 4);
            bf16x8 t;
#pragma unroll
            for (int j = 0; j < 8; j++) t[j] = (short)f2b(f[j]);
            a[m] = t;
        }
#pragma unroll
        for (int nb = 0; nb < 8; nb++) {
            bf16x8 b = *(const bf16x8*)&wl[(nb * 16 + lr) * 136 + kc + lk];
            acc[0][nb] = __builtin_amdgcn_mfma_f32_16x16x32_bf16(a[0], b, acc[0][nb], 0, 0, 0);
            acc[1][nb] = __builtin_amdgcn_mfma_f32_16x16x32_bf16(a[1], b, acc[1][nb], 0, 0, 0);
        }
    }
    int rq = (lane >> 4) * 4;
#pragma unroll
    for (int m = 0; m < 2; m++) {
#pragma unroll
        for (int r = 0; r < 4; r++) {
            long row = rowbase + m * 16 + rq + r;
            if (row < NN) {
#pragma unroll
                for (int nb = 0; nb < 8; nb++)
                    y1[row * 128 + nb * 16 + lr] = f2b(acc[m][nb][r]);
            }
        }
    }
}

// ---------------- GEMM2: y2 = bf16( h @ W2^T ), h bf16 [NN,128], W2 [64,128] ----------------
__global__ __launch_bounds__(256) void gemm2_k(const ushort* __restrict__ h,
                                               const float* __restrict__ W2,
                                               ushort* __restrict__ y2) {
    __shared__ ushort wl[64 * 136];
    int tid = threadIdx.x;
    for (int i = tid; i < 64 * 128; i += 256)
        wl[(i >> 7) * 136 + (i & 127)] = f2b(W2[i]);
    __syncthreads();

    int wave = tid >> 6, lane = tid & 63;
    int lr = lane & 15, lk = (lane >> 4) * 8;
    long rowbase = (long)blockIdx.x * 128 + wave * 32;

    f32x4 acc[2][4] = {};
    for (int kc = 0; kc < 128; kc += 32) {
        bf16x8 a[2];
#pragma unroll
        for (int m = 0; m < 2; m++) {
            long row = rowbase + m * 16 + lr;
            if (row > NN - 1) row = NN - 1;
            a[m] = *(const bf16x8*)(h + row * 128 + kc + lk);
        }
#pragma unroll
        for (int nb = 0; nb < 4; nb++) {
            bf16x8 b = *(const bf16x8*)&wl[(nb * 16 + lr) * 136 + kc + lk];
            acc[0][nb] = __builtin_amdgcn_mfma_f32_16x16x32_bf16(a[0], b, acc[0][nb], 0, 0, 0);
            acc[1][nb] = __builtin_amdgcn_mfma_f32_16x16x32_bf16(a[1], b, acc[1][nb], 0, 0, 0);
        }
    }
    int rq = (lane >> 4) * 4;
#pragma unroll
    for (int m = 0; m < 2; m++) {
#pragma unroll
        for (int r = 0; r < 4; r++) {
            long row = rowbase + m * 16 + rq + r;
            if (row < NN) {
#pragma unroll
                for (int nb = 0; nb < 4; nb++)
                    y2[row * 64 + nb * 16 + lr] = f2b(acc[m][nb][r]);
            }
        }
    }
}

// ---------------- pull aggregation: wave per node, quarter-wave per edge ----------------
// Out-of-range edge slots read the zero pad row (NN) -> no predication.
// Hi bf16 accumulated with raw bit_cast (junk low bits <= 2^-8 rel, within budget).

__global__ __launch_bounds__(256) void agg1_k(const ushort* __restrict__ y1,
                                              const int* __restrict__ nodeptr,
                                              const uint* __restrict__ col,
                                              const float* __restrict__ b1,
                                              ushort* __restrict__ h) {
    int wid = (blockIdx.x * 256 + threadIdx.x) >> 6;
    int lane = threadIdx.x & 63;
    if (wid >= NN) return;
    int s0 = nodeptr[wid], s1 = nodeptr[wid + 1];
    int q = lane >> 4, r = lane & 15;

    float aLo[4] = {}, aHi[4] = {};

    for (int i = s0; i < s1; i += 64) {
        int m = s1 - i; if (m > 64) m = 64;
        int sv = (lane < m) ? (int)col[i + lane] : NN;
        int jmax = (m + 3) >> 2;
        for (int j = 0; j < jmax; ++j) {
            int sj = __shfl(sv, 4 * j + q);
            uint4 u = *(const uint4*)(y1 + (size_t)sj * 128 + r * 8);
            aLo[0] += bflo(u.x); aHi[0] += bfraw(u.x);
            aLo[1] += bflo(u.y); aHi[1] += bfraw(u.y);
            aLo[2] += bflo(u.z); aHi[2] += bfraw(u.z);
            aLo[3] += bflo(u.w); aHi[3] += bfraw(u.w);
        }
    }
#pragma unroll
    for (int d = 0; d < 4; ++d) {
        aLo[d] += __shfl_xor(aLo[d], 16); aLo[d] += __shfl_xor(aLo[d], 32);
        aHi[d] += __shfl_xor(aHi[d], 16); aHi[d] += __shfl_xor(aHi[d], 32);
    }
    if (q == 0) {
        uint4 s = *(const uint4*)(y1 + (size_t)wid * 128 + r * 8);
        float4 bA = *(const float4*)(b1 + r * 8);
        float4 bB = *(const float4*)(b1 + r * 8 + 4);
        float v0 = fmaxf(aLo[0] + bflo(s.x) + bA.x, 0.f);
        float v1 = fmaxf(aHi[0] + bfhi(s.x) + bA.y, 0.f);
        float v2 = fmaxf(aLo[1] + bflo(s.y) + bA.z, 0.f);
        float v3 = fmaxf(aHi[1] + bfhi(s.y) + bA.w, 0.f);
        float v4 = fmaxf(aLo[2] + bflo(s.z) + bB.x, 0.f);
        float v5 = fmaxf(aHi[2] + bfhi(s.z) + bB.y, 0.f);
        float v6 = fmaxf(aLo[3] + bflo(s.w) + bB.z, 0.f);
        float v7 = fmaxf(aHi[3] + bfhi(s.w) + bB.w, 0.f);
        uint4 o;
        o.x = (uint)f2b(v0) | ((uint)f2b(v1) << 16);
        o.y = (uint)f2b(v2) | ((uint)f2b(v3) << 16);
        o.z = (uint)f2b(v4) | ((uint)f2b(v5) << 16);
        o.w = (uint)f2b(v6) | ((uint)f2b(v7) << 16);
        *(uint4*)(h + (size_t)wid * 128 + r * 8) = o;
    }
}

__global__ __launch_bounds__(256) void agg2_k(const ushort* __restrict__ y2,
                                              const int* __restrict__ nodeptr,
                                              const uint* __restrict__ col,
                                              const float* __restrict__ b2,
                                              float* __restrict__ out) {
    int wid = (blockIdx.x * 256 + threadIdx.x) >> 6;
    int lane = threadIdx.x & 63;
    if (wid >= NN) return;
    int s0 = nodeptr[wid], s1 = nodeptr[wid + 1];
    int q = lane >> 4, r = lane & 15;

    float aLo[2] = {}, aHi[2] = {};

    for (int i = s0; i < s1; i += 64) {
        int m = s1 - i; if (m > 64) m = 64;
        int sv = (lane < m) ? (int)col[i + lane] : NN;
        int jmax = (m + 3) >> 2;
        for (int j = 0; j < jmax; ++j) {
            int sj = __shfl(sv, 4 * j + q);
            uint2 u = *(const uint2*)(y2 + (size_t)sj * 64 + r * 4);
            aLo[0] += bflo(u.x); aHi[0] += bfraw(u.x);
            aLo[1] += bflo(u.y); aHi[1] += bfraw(u.y);
        }
    }
#pragma unroll
    for (int d = 0; d < 2; ++d) {
        aLo[d] += __shfl_xor(aLo[d], 16); aLo[d] += __shfl_xor(aLo[d], 32);
        aHi[d] += __shfl_xor(aHi[d], 16); aHi[d] += __shfl_xor(aHi[d], 32);
    }
    if (q == 0) {
        uint2 s = *(const uint2*)(y2 + (size_t)wid * 64 + r * 4);
        float4 bb = *(const float4*)(b2 + r * 4);
        float4 o;
        o.x = aLo[0] + bflo(s.x) + bb.x;
        o.y = aHi[0] + bfhi(s.x) + bb.y;
        o.z = aLo[1] + bflo(s.y) + bb.z;
        o.w = aHi[1] + bfhi(s.y) + bb.w;
        *(float4*)(out + (size_t)wid * 64 + r * 4) = o;
    }
}

// ---------------- launch ----------------

static constexpr size_t alup(size_t x) { return (x + 255) & ~(size_t)255; }
static constexpr size_t OFF_HIST  = 0;
static constexpr size_t OFF_PBASE = alup(OFF_HIST  + (size_t)NB * NBK * 4);
static constexpr size_t OFF_TOT   = alup(OFF_PBASE + (size_t)NB * NBK * 4);
static constexpr size_t OFF_GBASE = alup(OFF_TOT   + NBK * 4);
static constexpr size_t OFF_NPTR  = alup(OFF_GBASE + (NBK + 1) * 4);
static constexpr size_t OFF_BARR  = alup(OFF_NPTR  + (size_t)(NN + 1) * 4);
static constexpr size_t OFF_COL   = alup(OFF_BARR  + (size_t)NE * 4);
static constexpr size_t OFF_Y1    = alup(OFF_COL   + (size_t)NE * 4);
static constexpr size_t OFF_H     = alup(OFF_Y1 + (size_t)(NN + 1) * 128 * 2);
static constexpr size_t OFF_Y2    = alup(OFF_H  + (size_t)NN * 128 * 2);

extern "C" void kernel_launch(void* const* d_in, const int* in_sizes, int n_in,
                              void* d_out, int out_size, void* d_ws, size_t ws_size,
                              hipStream_t stream) {
    const float* x  = (const float*)d_in[0];
    const int*   ei = (const int*)d_in[1];
    const float* W1 = (const float*)d_in[2];
    const float* b1 = (const float*)d_in[3];
    const float* W2 = (const float*)d_in[4];
    const float* b2 = (const float*)d_in[5];
    float* out = (float*)d_out;
    char* ws = (char*)d_ws;

    int*  hist  = (int*)(ws + OFF_HIST);
    int*  pbase = (int*)(ws + OFF_PBASE);
    int*  tot   = (int*)(ws + OFF_TOT);
    int*  gbase = (int*)(ws + OFF_GBASE);
    int*  nptr  = (int*)(ws + OFF_NPTR);
    uint* barr  = (uint*)(ws + OFF_BARR);
    uint* colA  = (uint*)(ws + OFF_COL);
    ushort* y1 = (ushort*)(ws + OFF_Y1);
    ushort* hh = (ushort*)(ws + OFF_H);
    ushort* y2 = (ushort*)(ws + OFF_Y2);

    hipLaunchKernelGGL(hist2_k,  dim3(NB),  dim3(512),  0, stream, ei, hist);
    hipLaunchKernelGGL(pbase_k,  dim3(NBK), dim3(64),   0, stream, hist, pbase, tot);
    hipLaunchKernelGGL(bscan_k,  dim3(1),   dim3(1024), 0, stream, tot, gbase, nptr, y1, y2);
    hipLaunchKernelGGL(bfill2_k, dim3(NB),  dim3(512),  0, stream, ei, pbase, gbase, barr);
    hipLaunchKernelGGL(csr_k,    dim3(NBK), dim3(256),  0, stream, barr, gbase, nptr, colA);

    hipLaunchKernelGGL(gemm1_k, dim3(782),  dim3(256), 0, stream, x, W1, y1);
    hipLaunchKernelGGL(agg1_k,  dim3(25000),dim3(256), 0, stream, y1, nptr, colA, b1, hh);
    hipLaunchKernelGGL(gemm2_k, dim3(782),  dim3(256), 0, stream, hh, W2, y2);
    hipLaunchKernelGGL(agg2_k,  dim3(25000),dim3(256), 0, stream, y2, nptr, colA, b2, out);
}

// Round 7
// 263.856 us; speedup vs baseline: 18.5543x; 1.0767x over previous
//
#include <hip/hip_runtime.h>
#include <stdint.h>

#define NN 100000
#define NE 3200000
#define NBK 782          // ceil(NN/128) buckets of 128 dst nodes
#define NB  512          // sort blocks
#define CH  6250         // edges per sort block: 512*6250 = 3.2M = NE
#define CSRCAP 4800      // LDS staging capacity per bucket (mean 4096, 5-sigma ~4420)

typedef unsigned int uint;
typedef unsigned short ushort;
typedef __attribute__((ext_vector_type(8))) short bf16x8;
typedef __attribute__((ext_vector_type(4))) float f32x4;

static __device__ __forceinline__ float bflo(uint v) {
    uint u = v << 16; return __builtin_bit_cast(float, u);
}
static __device__ __forceinline__ float bfhi(uint v) {
    uint u = v & 0xffff0000u; return __builtin_bit_cast(float, u);
}
static __device__ __forceinline__ float bfraw(uint v) {   // hi bf16 with low-bit junk (<=2^-8 rel)
    return __builtin_bit_cast(float, v);
}
static __device__ __forceinline__ float b2f(ushort v) {
    uint u = ((uint)v) << 16; return __builtin_bit_cast(float, u);
}
static __device__ __forceinline__ ushort f2b(float f) {  // RNE fp32->bf16
    uint u = __builtin_bit_cast(uint, f);
    u += 0x7fffu + ((u >> 16) & 1u);
    return (ushort)(u >> 16);
}
static __device__ __forceinline__ int wscan(int v, int lane) {  // 64-lane inclusive
#pragma unroll
    for (int off = 1; off < 64; off <<= 1) {
        int t = __shfl_up(v, off);
        if (lane >= off) v += t;
    }
    return v;
}

// ---------------- deterministic bucket counting-sort ----------------

__global__ __launch_bounds__(512) void hist2_k(const int* __restrict__ ei,
                                               int* __restrict__ hist) {
    __shared__ int hl[NBK];
    int tid = threadIdx.x, b = blockIdx.x;
    for (int k = tid; k < NBK; k += 512) hl[k] = 0;
    __syncthreads();
    int base = b * CH;
    for (int i = base + tid; i < base + CH; i += 512)
        atomicAdd(&hl[ei[NE + i] >> 7], 1);
    __syncthreads();
    for (int k = tid; k < NBK; k += 512) hist[b * NBK + k] = hl[k];
}

__global__ __launch_bounds__(64) void pbase_k(const int* __restrict__ hist,
                                              int* __restrict__ pbase,
                                              int* __restrict__ totals) {
    int k = blockIdx.x, lane = threadIdx.x;
    int carry = 0;
#pragma unroll
    for (int c = 0; c < NB / 64; ++c) {
        int b = c * 64 + lane;
        int v = hist[b * NBK + k];
        int incl = wscan(v, lane);
        pbase[b * NBK + k] = carry + incl - v;
        carry += __shfl(incl, 63);
    }
    if (lane == 0) totals[k] = carry;
}

// scan bucket totals -> gbase; also zero the pad rows (index NN) of y1/y2.
__global__ __launch_bounds__(1024) void bscan_k(const int* __restrict__ totals,
                                                int* __restrict__ gbase,
                                                int* __restrict__ nodeptr,
                                                ushort* __restrict__ y1,
                                                ushort* __restrict__ y2) {
    __shared__ int sd[1024];
    int t = threadIdx.x;
    int v = (t < NBK) ? totals[t] : 0;
    sd[t] = v;
    __syncthreads();
    for (int off = 1; off < 1024; off <<= 1) {
        int u = (t >= off) ? sd[t - off] : 0;
        __syncthreads();
        sd[t] += u;
        __syncthreads();
    }
    int excl = sd[t] - v;
    if (t < NBK) gbase[t] = excl;
    if (t == 0) { gbase[NBK] = NE; nodeptr[NN] = NE; }
    if (t < 64) ((uint*)(y1 + (size_t)NN * 128))[t] = 0;   // zero pad row (256B)
    if (t < 32) ((uint*)(y2 + (size_t)NN * 64))[t] = 0;    // zero pad row (128B)
}

// direct scatter with LDS cursors seeded from gbase+pbase.
__global__ __launch_bounds__(512) void bfill2_k(const int* __restrict__ ei,
                                                const int* __restrict__ pbase,
                                                const int* __restrict__ gbase,
                                                uint* __restrict__ barr) {
    __shared__ int cur[NBK];
    int tid = threadIdx.x, b = blockIdx.x;
    for (int k = tid; k < NBK; k += 512)
        cur[k] = gbase[k] + pbase[b * NBK + k];
    __syncthreads();
    int base = b * CH;
    for (int i = base + tid; i < base + CH; i += 512) {
        int s = ei[i], d = ei[NE + i];
        int pos = atomicAdd(&cur[d >> 7], 1);       // LDS atomic only
        barr[pos] = ((uint)(d & 127) << 17) | (uint)s;
    }
}

// within-bucket counting sort via LDS staging (single global read of the bucket).
__global__ __launch_bounds__(256) void csr_k(const uint* __restrict__ barr,
                                             const int* __restrict__ gbase,
                                             int* __restrict__ nodeptr,
                                             uint* __restrict__ col) {
    __shared__ uint stg[CSRCAP];
    __shared__ int cnt[128], cur[128];
    int tid = threadIdx.x;
    int blk = blockIdx.x;
    int s0 = gbase[blk], s1 = gbase[blk + 1];
    int n = s1 - s0;
    bool fits = (n <= CSRCAP);
    if (tid < 128) cnt[tid] = 0;
    __syncthreads();
    if (fits) {
        for (int i = tid; i < n; i += 256) {
            uint e = barr[s0 + i];
            stg[i] = e;
            atomicAdd(&cnt[e >> 17], 1);
        }
    } else {
        for (int i = s0 + tid; i < s1; i += 256)
            atomicAdd(&cnt[barr[i] >> 17], 1);
    }
    __syncthreads();
    if (tid < 64) {
        int c0 = cnt[2 * tid], c1 = cnt[2 * tid + 1];
        int s = c0 + c1;
        int incl = wscan(s, tid);
        int excl = incl - s;
        cur[2 * tid] = excl;
        cur[2 * tid + 1] = excl + c0;
        int node = blk * 128 + 2 * tid;
        if (node < NN)     nodeptr[node]     = s0 + excl;
        if (node + 1 < NN) nodeptr[node + 1] = s0 + excl + c0;
    }
    __syncthreads();
    if (fits) {
        for (int i = tid; i < n; i += 256) {
            uint e = stg[i];
            int pos = s0 + atomicAdd(&cur[e >> 17], 1);
            col[pos] = e & 0x1FFFF;
        }
    } else {
        for (int i = s0 + tid; i < s1; i += 256) {
            uint e = barr[i];
            int pos = s0 + atomicAdd(&cur[e >> 17], 1);
            col[pos] = e & 0x1FFFF;
        }
    }
}

// ---------------- GEMM1: y1 = bf16( x @ W1^T ), x fp32 [NN,128] ----------------
__global__ __launch_bounds__(256) void gemm1_k(const float* __restrict__ x,
                                               const float* __restrict__ W1,
                                               ushort* __restrict__ y1) {
    __shared__ ushort wl[128 * 136];
    int tid = threadIdx.x;
    for (int i = tid; i < 128 * 128; i += 256)
        wl[(i >> 7) * 136 + (i & 127)] = f2b(W1[i]);
    __syncthreads();

    int wave = tid >> 6, lane = tid & 63;
    int lr = lane & 15, lk = (lane >> 4) * 8;
    long rowbase = (long)blockIdx.x * 128 + wave * 32;

    f32x4 acc[2][8] = {};
    for (int kc = 0; kc < 128; kc += 32) {
        bf16x8 a[2];
#pragma unroll
        for (int m = 0; m < 2; m++) {
            long row = rowbase + m * 16 + lr;
            if (row > NN - 1) row = NN - 1;
            const float* p = x + row * 128 + kc + lk;
            float f[8];
            *(float4*)(f)     = *(const float4*)(p);
            *(float4*)(f + 4) = *(const float4*)(p + 4);
            bf16x8 t;
#pragma unroll
            for (int j = 0; j < 8; j++) t[j] = (short)f2b(f[j]);
            a[m] = t;
        }
#pragma unroll
        for (int nb = 0; nb < 8; nb++) {
            bf16x8 b = *(const bf16x8*)&wl[(nb * 16 + lr) * 136 + kc + lk];
            acc[0][nb] = __builtin_amdgcn_mfma_f32_16x16x32_bf16(a[0], b, acc[0][nb], 0, 0, 0);
            acc[1][nb] = __builtin_amdgcn_mfma_f32_16x16x32_bf16(a[1], b, acc[1][nb], 0, 0, 0);
        }
    }
    int rq = (lane >> 4) * 4;
#pragma unroll
    for (int m = 0; m < 2; m++) {
#pragma unroll
        for (int r = 0; r < 4; r++) {
            long row = rowbase + m * 16 + rq + r;
            if (row < NN) {
#pragma unroll
                for (int nb = 0; nb < 8; nb++)
                    y1[row * 128 + nb * 16 + lr] = f2b(acc[m][nb][r]);
            }
        }
    }
}

// ---------------- GEMM2: y2 = bf16( h @ W2^T ), h bf16 [NN,128], W2 [64,128] ----------------
__global__ __launch_bounds__(256) void gemm2_k(const ushort* __restrict__ h,
                                               const float* __restrict__ W2,
                                               ushort* __restrict__ y2) {
    __shared__ ushort wl[64 * 136];
    int tid = threadIdx.x;
    for (int i = tid; i < 64 * 128; i += 256)
        wl[(i >> 7) * 136 + (i & 127)] = f2b(W2[i]);
    __syncthreads();

    int wave = tid >> 6, lane = tid & 63;
    int lr = lane & 15, lk = (lane >> 4) * 8;
    long rowbase = (long)blockIdx.x * 128 + wave * 32;

    f32x4 acc[2][4] = {};
    for (int kc = 0; kc < 128; kc += 32) {
        bf16x8 a[2];
#pragma unroll
        for (int m = 0; m < 2; m++) {
            long row = rowbase + m * 16 + lr;
            if (row > NN - 1) row = NN - 1;
            a[m] = *(const bf16x8*)(h + row * 128 + kc + lk);
        }
#pragma unroll
        for (int nb = 0; nb < 4; nb++) {
            bf16x8 b = *(const bf16x8*)&wl[(nb * 16 + lr) * 136 + kc + lk];
            acc[0][nb] = __builtin_amdgcn_mfma_f32_16x16x32_bf16(a[0], b, acc[0][nb], 0, 0, 0);
            acc[1][nb] = __builtin_amdgcn_mfma_f32_16x16x32_bf16(a[1], b, acc[1][nb], 0, 0, 0);
        }
    }
    int rq = (lane >> 4) * 4;
#pragma unroll
    for (int m = 0; m < 2; m++) {
#pragma unroll
        for (int r = 0; r < 4; r++) {
            long row = rowbase + m * 16 + rq + r;
            if (row < NN) {
#pragma unroll
                for (int nb = 0; nb < 4; nb++)
                    y2[row * 64 + nb * 16 + lr] = f2b(acc[m][nb][r]);
            }
        }
    }
}

// ---------------- pull aggregation: wave per node, quarter-wave per edge ----------------
// 4-deep explicit memory pipeline: 4 independent gathers in flight per wave.
// Out-of-range slots read the zero pad row (NN) -> no predication, L1-hot.

__global__ __launch_bounds__(256) void agg1_k(const ushort* __restrict__ y1,
                                              const int* __restrict__ nodeptr,
                                              const uint* __restrict__ col,
                                              const float* __restrict__ b1,
                                              ushort* __restrict__ h) {
    int wid = (blockIdx.x * 256 + threadIdx.x) >> 6;
    int lane = threadIdx.x & 63;
    if (wid >= NN) return;
    int s0 = nodeptr[wid], s1 = nodeptr[wid + 1];
    int q = lane >> 4, r = lane & 15;

    float aLo[4] = {}, aHi[4] = {};
    const ushort* yr = y1 + r * 8;

    for (int i = s0; i < s1; i += 64) {
        int m = s1 - i; if (m > 64) m = 64;
        int sv = (lane < m) ? (int)col[i + lane] : NN;
        int jg = (m + 15) >> 4;                    // groups of 16 edges
        for (int g = 0; g < jg; ++g) {
            int e0 = 16 * g + q;
            int sj0 = __shfl(sv, e0);
            int sj1 = __shfl(sv, e0 + 4);
            int sj2 = __shfl(sv, e0 + 8);
            int sj3 = __shfl(sv, e0 + 12);
            uint4 u0 = *(const uint4*)(yr + (size_t)sj0 * 128);
            uint4 u1 = *(const uint4*)(yr + (size_t)sj1 * 128);
            uint4 u2 = *(const uint4*)(yr + (size_t)sj2 * 128);
            uint4 u3 = *(const uint4*)(yr + (size_t)sj3 * 128);
            aLo[0] += bflo(u0.x); aHi[0] += bfraw(u0.x);
            aLo[1] += bflo(u0.y); aHi[1] += bfraw(u0.y);
            aLo[2] += bflo(u0.z); aHi[2] += bfraw(u0.z);
            aLo[3] += bflo(u0.w); aHi[3] += bfraw(u0.w);
            aLo[0] += bflo(u1.x); aHi[0] += bfraw(u1.x);
            aLo[1] += bflo(u1.y); aHi[1] += bfraw(u1.y);
            aLo[2] += bflo(u1.z); aHi[2] += bfraw(u1.z);
            aLo[3] += bflo(u1.w); aHi[3] += bfraw(u1.w);
            aLo[0] += bflo(u2.x); aHi[0] += bfraw(u2.x);
            aLo[1] += bflo(u2.y); aHi[1] += bfraw(u2.y);
            aLo[2] += bflo(u2.z); aHi[2] += bfraw(u2.z);
            aLo[3] += bflo(u2.w); aHi[3] += bfraw(u2.w);
            aLo[0] += bflo(u3.x); aHi[0] += bfraw(u3.x);
            aLo[1] += bflo(u3.y); aHi[1] += bfraw(u3.y);
            aLo[2] += bflo(u3.z); aHi[2] += bfraw(u3.z);
            aLo[3] += bflo(u3.w); aHi[3] += bfraw(u3.w);
        }
    }
#pragma unroll
    for (int d = 0; d < 4; ++d) {
        aLo[d] += __shfl_xor(aLo[d], 16); aLo[d] += __shfl_xor(aLo[d], 32);
        aHi[d] += __shfl_xor(aHi[d], 16); aHi[d] += __shfl_xor(aHi[d], 32);
    }
    if (q == 0) {
        uint4 s = *(const uint4*)(y1 + (size_t)wid * 128 + r * 8);
        float4 bA = *(const float4*)(b1 + r * 8);
        float4 bB = *(const float4*)(b1 + r * 8 + 4);
        float v0 = fmaxf(aLo[0] + bflo(s.x) + bA.x, 0.f);
        float v1 = fmaxf(aHi[0] + bfhi(s.x) + bA.y, 0.f);
        float v2 = fmaxf(aLo[1] + bflo(s.y) + bA.z, 0.f);
        float v3 = fmaxf(aHi[1] + bfhi(s.y) + bA.w, 0.f);
        float v4 = fmaxf(aLo[2] + bflo(s.z) + bB.x, 0.f);
        float v5 = fmaxf(aHi[2] + bfhi(s.z) + bB.y, 0.f);
        float v6 = fmaxf(aLo[3] + bflo(s.w) + bB.z, 0.f);
        float v7 = fmaxf(aHi[3] + bfhi(s.w) + bB.w, 0.f);
        uint4 o;
        o.x = (uint)f2b(v0) | ((uint)f2b(v1) << 16);
        o.y = (uint)f2b(v2) | ((uint)f2b(v3) << 16);
        o.z = (uint)f2b(v4) | ((uint)f2b(v5) << 16);
        o.w = (uint)f2b(v6) | ((uint)f2b(v7) << 16);
        *(uint4*)(h + (size_t)wid * 128 + r * 8) = o;
    }
}

__global__ __launch_bounds__(256) void agg2_k(const ushort* __restrict__ y2,
                                              const int* __restrict__ nodeptr,
                                              const uint* __restrict__ col,
                                              const float* __restrict__ b2,
                                              float* __restrict__ out) {
    int wid = (blockIdx.x * 256 + threadIdx.x) >> 6;
    int lane = threadIdx.x & 63;
    if (wid >= NN) return;
    int s0 = nodeptr[wid], s1 = nodeptr[wid + 1];
    int q = lane >> 4, r = lane & 15;

    float aLo[2] = {}, aHi[2] = {};
    const ushort* yr = y2 + r * 4;

    for (int i = s0; i < s1; i += 64) {
        int m = s1 - i; if (m > 64) m = 64;
        int sv = (lane < m) ? (int)col[i + lane] : NN;
        int jg = (m + 15) >> 4;
        for (int g = 0; g < jg; ++g) {
            int e0 = 16 * g + q;
            int sj0 = __shfl(sv, e0);
            int sj1 = __shfl(sv, e0 + 4);
            int sj2 = __shfl(sv, e0 + 8);
            int sj3 = __shfl(sv, e0 + 12);
            uint2 u0 = *(const uint2*)(yr + (size_t)sj0 * 64);
            uint2 u1 = *(const uint2*)(yr + (size_t)sj1 * 64);
            uint2 u2 = *(const uint2*)(yr + (size_t)sj2 * 64);
            uint2 u3 = *(const uint2*)(yr + (size_t)sj3 * 64);
            aLo[0] += bflo(u0.x); aHi[0] += bfraw(u0.x);
            aLo[1] += bflo(u0.y); aHi[1] += bfraw(u0.y);
            aLo[0] += bflo(u1.x); aHi[0] += bfraw(u1.x);
            aLo[1] += bflo(u1.y); aHi[1] += bfraw(u1.y);
            aLo[0] += bflo(u2.x); aHi[0] += bfraw(u2.x);
            aLo[1] += bflo(u2.y); aHi[1] += bfraw(u2.y);
            aLo[0] += bflo(u3.x); aHi[0] += bfraw(u3.x);
            aLo[1] += bflo(u3.y); aHi[1] += bfraw(u3.y);
        }
    }
#pragma unroll
    for (int d = 0; d < 2; ++d) {
        aLo[d] += __shfl_xor(aLo[d], 16); aLo[d] += __shfl_xor(aLo[d], 32);
        aHi[d] += __shfl_xor(aHi[d], 16); aHi[d] += __shfl_xor(aHi[d], 32);
    }
    if (q == 0) {
        uint2 s = *(const uint2*)(y2 + (size_t)wid * 64 + r * 4);
        float4 bb = *(const float4*)(b2 + r * 4);
        float4 o;
        o.x = aLo[0] + bflo(s.x) + bb.x;
        o.y = aHi[0] + bfhi(s.x) + bb.y;
        o.z = aLo[1] + bflo(s.y) + bb.z;
        o.w = aHi[1] + bfhi(s.y) + bb.w;
        *(float4*)(out + (size_t)wid * 64 + r * 4) = o;
    }
}

// ---------------- launch ----------------

static constexpr size_t alup(size_t x) { return (x + 255) & ~(size_t)255; }
static constexpr size_t OFF_HIST  = 0;
static constexpr size_t OFF_PBASE = alup(OFF_HIST  + (size_t)NB * NBK * 4);
static constexpr size_t OFF_TOT   = alup(OFF_PBASE + (size_t)NB * NBK * 4);
static constexpr size_t OFF_GBASE = alup(OFF_TOT   + NBK * 4);
static constexpr size_t OFF_NPTR  = alup(OFF_GBASE + (NBK + 1) * 4);
static constexpr size_t OFF_BARR  = alup(OFF_NPTR  + (size_t)(NN + 1) * 4);
static constexpr size_t OFF_COL   = alup(OFF_BARR  + (size_t)NE * 4);
static constexpr size_t OFF_Y1    = alup(OFF_COL   + (size_t)NE * 4);
static constexpr size_t OFF_H     = alup(OFF_Y1 + (size_t)(NN + 1) * 128 * 2);
static constexpr size_t OFF_Y2    = alup(OFF_H  + (size_t)NN * 128 * 2);

extern "C" void kernel_launch(void* const* d_in, const int* in_sizes, int n_in,
                              void* d_out, int out_size, void* d_ws, size_t ws_size,
                              hipStream_t stream) {
    const float* x  = (const float*)d_in[0];
    const int*   ei = (const int*)d_in[1];
    const float* W1 = (const float*)d_in[2];
    const float* b1 = (const float*)d_in[3];
    const float* W2 = (const float*)d_in[4];
    const float* b2 = (const float*)d_in[5];
    float* out = (float*)d_out;
    char* ws = (char*)d_ws;

    int*  hist  = (int*)(ws + OFF_HIST);
    int*  pbase = (int*)(ws + OFF_PBASE);
    int*  tot   = (int*)(ws + OFF_TOT);
    int*  gbase = (int*)(ws + OFF_GBASE);
    int*  nptr  = (int*)(ws + OFF_NPTR);
    uint* barr  = (uint*)(ws + OFF_BARR);
    uint* colA  = (uint*)(ws + OFF_COL);
    ushort* y1 = (ushort*)(ws + OFF_Y1);
    ushort* hh = (ushort*)(ws + OFF_H);
    ushort* y2 = (ushort*)(ws + OFF_Y2);

    hipLaunchKernelGGL(hist2_k,  dim3(NB),  dim3(512),  0, stream, ei, hist);
    hipLaunchKernelGGL(pbase_k,  dim3(NBK), dim3(64),   0, stream, hist, pbase, tot);
    hipLaunchKernelGGL(bscan_k,  dim3(1),   dim3(1024), 0, stream, tot, gbase, nptr, y1, y2);
    hipLaunchKernelGGL(bfill2_k, dim3(NB),  dim3(512),  0, stream, ei, pbase, gbase, barr);
    hipLaunchKernelGGL(csr_k,    dim3(NBK), dim3(256),  0, stream, barr, gbase, nptr, colA);

    hipLaunchKernelGGL(gemm1_k, dim3(782),  dim3(256), 0, stream, x, W1, y1);
    hipLaunchKernelGGL(agg1_k,  dim3(25000),dim3(256), 0, stream, y1, nptr, colA, b1, hh);
    hipLaunchKernelGGL(gemm2_k, dim3(782),  dim3(256), 0, stream, hh, W2, y2);
    hipLaunchKernelGGL(agg2_k,  dim3(25000),dim3(256), 0, stream, y2, nptr, colA, b2, out);
}

// Round 8
// 258.380 us; speedup vs baseline: 18.9475x; 1.0212x over previous
//
#include <hip/hip_runtime.h>
#include <stdint.h>

#define NN 100000
#define NE 3200000
#define NBK 782          // ceil(NN/128) buckets of 128 dst nodes
#define NB  512          // sort blocks
#define CH  6250         // edges per sort block: 512*6250 = 3.2M = NE
#define CSRCAP 4800      // LDS staging capacity per bucket (mean 4096, 5-sigma ~4420)

typedef unsigned int uint;
typedef unsigned short ushort;
typedef __attribute__((ext_vector_type(8))) short bf16x8;
typedef __attribute__((ext_vector_type(4))) float f32x4;

static __device__ __forceinline__ float bflo(uint v) {
    uint u = v << 16; return __builtin_bit_cast(float, u);
}
static __device__ __forceinline__ float bfhi(uint v) {
    uint u = v & 0xffff0000u; return __builtin_bit_cast(float, u);
}
static __device__ __forceinline__ float bfraw(uint v) {   // hi bf16 with low-bit junk (<=2^-9 rel)
    return __builtin_bit_cast(float, v);
}
static __device__ __forceinline__ ushort f2b(float f) {  // RNE fp32->bf16
    uint u = __builtin_bit_cast(uint, f);
    u += 0x7fffu + ((u >> 16) & 1u);
    return (ushort)(u >> 16);
}
static __device__ __forceinline__ int wscan(int v, int lane) {  // 64-lane inclusive
#pragma unroll
    for (int off = 1; off < 64; off <<= 1) {
        int t = __shfl_up(v, off);
        if (lane >= off) v += t;
    }
    return v;
}

// ---------------- deterministic bucket counting-sort ----------------

__global__ __launch_bounds__(512) void hist2_k(const int* __restrict__ ei,
                                               int* __restrict__ hist) {
    __shared__ int hl[NBK];
    int tid = threadIdx.x, b = blockIdx.x;
    for (int k = tid; k < NBK; k += 512) hl[k] = 0;
    __syncthreads();
    int base = b * CH;
    for (int i = base + tid; i < base + CH; i += 512)
        atomicAdd(&hl[ei[NE + i] >> 7], 1);
    __syncthreads();
    for (int k = tid; k < NBK; k += 512) hist[b * NBK + k] = hl[k];
}

__global__ __launch_bounds__(64) void pbase_k(const int* __restrict__ hist,
                                              int* __restrict__ pbase,
                                              int* __restrict__ totals) {
    int k = blockIdx.x, lane = threadIdx.x;
    int carry = 0;
#pragma unroll
    for (int c = 0; c < NB / 64; ++c) {
        int b = c * 64 + lane;
        int v = hist[b * NBK + k];
        int incl = wscan(v, lane);
        pbase[b * NBK + k] = carry + incl - v;
        carry += __shfl(incl, 63);
    }
    if (lane == 0) totals[k] = carry;
}

// scan bucket totals -> gbase; also zero the pad rows (index NN) of y1a/y1b/y2.
__global__ __launch_bounds__(1024) void bscan_k(const int* __restrict__ totals,
                                                int* __restrict__ gbase,
                                                int* __restrict__ nodeptr,
                                                ushort* __restrict__ y1a,
                                                ushort* __restrict__ y1b,
                                                ushort* __restrict__ y2) {
    __shared__ int sd[1024];
    int t = threadIdx.x;
    int v = (t < NBK) ? totals[t] : 0;
    sd[t] = v;
    __syncthreads();
    for (int off = 1; off < 1024; off <<= 1) {
        int u = (t >= off) ? sd[t - off] : 0;
        __syncthreads();
        sd[t] += u;
        __syncthreads();
    }
    int excl = sd[t] - v;
    if (t < NBK) gbase[t] = excl;
    if (t == 0) { gbase[NBK] = NE; nodeptr[NN] = NE; }
    if (t < 32)              ((uint*)(y1a + (size_t)NN * 64))[t] = 0;
    else if (t < 64)         ((uint*)(y1b + (size_t)NN * 64))[t - 32] = 0;
    else if (t < 96)         ((uint*)(y2  + (size_t)NN * 64))[t - 64] = 0;
}

// direct scatter with LDS cursors seeded from gbase+pbase.
__global__ __launch_bounds__(512) void bfill2_k(const int* __restrict__ ei,
                                                const int* __restrict__ pbase,
                                                const int* __restrict__ gbase,
                                                uint* __restrict__ barr) {
    __shared__ int cur[NBK];
    int tid = threadIdx.x, b = blockIdx.x;
    for (int k = tid; k < NBK; k += 512)
        cur[k] = gbase[k] + pbase[b * NBK + k];
    __syncthreads();
    int base = b * CH;
    for (int i = base + tid; i < base + CH; i += 512) {
        int s = ei[i], d = ei[NE + i];
        int pos = atomicAdd(&cur[d >> 7], 1);       // LDS atomic only
        barr[pos] = ((uint)(d & 127) << 17) | (uint)s;
    }
}

// within-bucket counting sort via LDS staging (single global read of the bucket).
__global__ __launch_bounds__(256) void csr_k(const uint* __restrict__ barr,
                                             const int* __restrict__ gbase,
                                             int* __restrict__ nodeptr,
                                             uint* __restrict__ col) {
    __shared__ uint stg[CSRCAP];
    __shared__ int cnt[128], cur[128];
    int tid = threadIdx.x;
    int blk = blockIdx.x;
    int s0 = gbase[blk], s1 = gbase[blk + 1];
    int n = s1 - s0;
    bool fits = (n <= CSRCAP);
    if (tid < 128) cnt[tid] = 0;
    __syncthreads();
    if (fits) {
        for (int i = tid; i < n; i += 256) {
            uint e = barr[s0 + i];
            stg[i] = e;
            atomicAdd(&cnt[e >> 17], 1);
        }
    } else {
        for (int i = s0 + tid; i < s1; i += 256)
            atomicAdd(&cnt[barr[i] >> 17], 1);
    }
    __syncthreads();
    if (tid < 64) {
        int c0 = cnt[2 * tid], c1 = cnt[2 * tid + 1];
        int s = c0 + c1;
        int incl = wscan(s, tid);
        int excl = incl - s;
        cur[2 * tid] = excl;
        cur[2 * tid + 1] = excl + c0;
        int node = blk * 128 + 2 * tid;
        if (node < NN)     nodeptr[node]     = s0 + excl;
        if (node + 1 < NN) nodeptr[node + 1] = s0 + excl + c0;
    }
    __syncthreads();
    if (fits) {
        for (int i = tid; i < n; i += 256) {
            uint e = stg[i];
            int pos = s0 + atomicAdd(&cur[e >> 17], 1);
            col[pos] = e & 0x1FFFF;
        }
    } else {
        for (int i = s0 + tid; i < s1; i += 256) {
            uint e = barr[i];
            int pos = s0 + atomicAdd(&cur[e >> 17], 1);
            col[pos] = e & 0x1FFFF;
        }
    }
}

// ---------------- GEMM1: y1 = bf16( x @ W1^T ), planar halves ----------------
__global__ __launch_bounds__(256) void gemm1_k(const float* __restrict__ x,
                                               const float* __restrict__ W1,
                                               ushort* __restrict__ y1a,
                                               ushort* __restrict__ y1b) {
    __shared__ ushort wl[128 * 136];
    int tid = threadIdx.x;
    for (int i = tid; i < 128 * 128; i += 256)
        wl[(i >> 7) * 136 + (i & 127)] = f2b(W1[i]);
    __syncthreads();

    int wave = tid >> 6, lane = tid & 63;
    int lr = lane & 15, lk = (lane >> 4) * 8;
    long rowbase = (long)blockIdx.x * 128 + wave * 32;

    f32x4 acc[2][8] = {};
    for (int kc = 0; kc < 128; kc += 32) {
        bf16x8 a[2];
#pragma unroll
        for (int m = 0; m < 2; m++) {
            long row = rowbase + m * 16 + lr;
            if (row > NN - 1) row = NN - 1;
            const float* p = x + row * 128 + kc + lk;
            float f[8];
            *(float4*)(f)     = *(const float4*)(p);
            *(float4*)(f + 4) = *(const float4*)(p + 4);
            bf16x8 t;
#pragma unroll
            for (int j = 0; j < 8; j++) t[j] = (short)f2b(f[j]);
            a[m] = t;
        }
#pragma unroll
        for (int nb = 0; nb < 8; nb++) {
            bf16x8 b = *(const bf16x8*)&wl[(nb * 16 + lr) * 136 + kc + lk];
            acc[0][nb] = __builtin_amdgcn_mfma_f32_16x16x32_bf16(a[0], b, acc[0][nb], 0, 0, 0);
            acc[1][nb] = __builtin_amdgcn_mfma_f32_16x16x32_bf16(a[1], b, acc[1][nb], 0, 0, 0);
        }
    }
    int rq = (lane >> 4) * 4;
#pragma unroll
    for (int m = 0; m < 2; m++) {
#pragma unroll
        for (int r = 0; r < 4; r++) {
            long row = rowbase + m * 16 + rq + r;
            if (row < NN) {
#pragma unroll
                for (int nb = 0; nb < 8; nb++) {
                    ushort v = f2b(acc[m][nb][r]);
                    if (nb < 4) y1a[row * 64 + nb * 16 + lr] = v;
                    else        y1b[row * 64 + (nb - 4) * 16 + lr] = v;
                }
            }
        }
    }
}

// ---------------- GEMM2: y2 = bf16( h @ W2^T ), h in planar halves ----------------
__global__ __launch_bounds__(256) void gemm2_k(const ushort* __restrict__ ha,
                                               const ushort* __restrict__ hb,
                                               const float* __restrict__ W2,
                                               ushort* __restrict__ y2) {
    __shared__ ushort wl[64 * 136];
    int tid = threadIdx.x;
    for (int i = tid; i < 64 * 128; i += 256)
        wl[(i >> 7) * 136 + (i & 127)] = f2b(W2[i]);
    __syncthreads();

    int wave = tid >> 6, lane = tid & 63;
    int lr = lane & 15, lk = (lane >> 4) * 8;
    long rowbase = (long)blockIdx.x * 128 + wave * 32;

    f32x4 acc[2][4] = {};
#pragma unroll
    for (int kc = 0; kc < 128; kc += 32) {
        const ushort* hsrc = (kc < 64) ? ha : hb;
        int koff = kc & 63;
        bf16x8 a[2];
#pragma unroll
        for (int m = 0; m < 2; m++) {
            long row = rowbase + m * 16 + lr;
            if (row > NN - 1) row = NN - 1;
            a[m] = *(const bf16x8*)(hsrc + row * 64 + koff + lk);
        }
#pragma unroll
        for (int nb = 0; nb < 4; nb++) {
            bf16x8 b = *(const bf16x8*)&wl[(nb * 16 + lr) * 136 + kc + lk];
            acc[0][nb] = __builtin_amdgcn_mfma_f32_16x16x32_bf16(a[0], b, acc[0][nb], 0, 0, 0);
            acc[1][nb] = __builtin_amdgcn_mfma_f32_16x16x32_bf16(a[1], b, acc[1][nb], 0, 0, 0);
        }
    }
    int rq = (lane >> 4) * 4;
#pragma unroll
    for (int m = 0; m < 2; m++) {
#pragma unroll
        for (int r = 0; r < 4; r++) {
            long row = rowbase + m * 16 + rq + r;
            if (row < NN) {
#pragma unroll
                for (int nb = 0; nb < 4; nb++)
                    y2[row * 64 + nb * 16 + lr] = f2b(acc[m][nb][r]);
            }
        }
    }
}

// ---------------- pull aggregation: wave per node, OCT (8 lanes) per edge ----------------
// 128B rows: 8 lanes x 16B per row -> 8 edges per wave-load, 4-deep pipeline
// = 32 edges in flight. Out-of-range slots read the zero pad row (NN).

// Layer-1 half: yh [NN+1][64] bf16 -> hh = bf16(relu(self + agg + bias_half))
__global__ __launch_bounds__(256) void agg1h_k(const ushort* __restrict__ yh,
                                               const int* __restrict__ nodeptr,
                                               const uint* __restrict__ col,
                                               const float* __restrict__ bh,
                                               ushort* __restrict__ hh) {
    int wid = (blockIdx.x * 256 + threadIdx.x) >> 6;
    int lane = threadIdx.x & 63;
    if (wid >= NN) return;
    int s0 = nodeptr[wid], s1 = nodeptr[wid + 1];
    int o = lane >> 3, r = lane & 7;

    float aLo[4] = {}, aHi[4] = {};
    const ushort* yr = yh + r * 8;

    for (int i = s0; i < s1; i += 64) {
        int m = s1 - i; if (m > 64) m = 64;
        int sv = (lane < m) ? (int)col[i + lane] : NN;
        int jg = (m + 31) >> 5;                    // groups of 32 edges
        for (int g = 0; g < jg; ++g) {
            int e0 = 32 * g + o;
            int sj0 = __shfl(sv, e0);
            int sj1 = __shfl(sv, e0 + 8);
            int sj2 = __shfl(sv, e0 + 16);
            int sj3 = __shfl(sv, e0 + 24);
            uint4 u0 = *(const uint4*)(yr + (size_t)sj0 * 64);
            uint4 u1 = *(const uint4*)(yr + (size_t)sj1 * 64);
            uint4 u2 = *(const uint4*)(yr + (size_t)sj2 * 64);
            uint4 u3 = *(const uint4*)(yr + (size_t)sj3 * 64);
            aLo[0] += bflo(u0.x); aHi[0] += bfraw(u0.x);
            aLo[1] += bflo(u0.y); aHi[1] += bfraw(u0.y);
            aLo[2] += bflo(u0.z); aHi[2] += bfraw(u0.z);
            aLo[3] += bflo(u0.w); aHi[3] += bfraw(u0.w);
            aLo[0] += bflo(u1.x); aHi[0] += bfraw(u1.x);
            aLo[1] += bflo(u1.y); aHi[1] += bfraw(u1.y);
            aLo[2] += bflo(u1.z); aHi[2] += bfraw(u1.z);
            aLo[3] += bflo(u1.w); aHi[3] += bfraw(u1.w);
            aLo[0] += bflo(u2.x); aHi[0] += bfraw(u2.x);
            aLo[1] += bflo(u2.y); aHi[1] += bfraw(u2.y);
            aLo[2] += bflo(u2.z); aHi[2] += bfraw(u2.z);
            aLo[3] += bflo(u2.w); aHi[3] += bfraw(u2.w);
            aLo[0] += bflo(u3.x); aHi[0] += bfraw(u3.x);
            aLo[1] += bflo(u3.y); aHi[1] += bfraw(u3.y);
            aLo[2] += bflo(u3.z); aHi[2] += bfraw(u3.z);
            aLo[3] += bflo(u3.w); aHi[3] += bfraw(u3.w);
        }
    }
#pragma unroll
    for (int d = 0; d < 4; ++d) {
        aLo[d] += __shfl_xor(aLo[d], 8);  aHi[d] += __shfl_xor(aHi[d], 8);
        aLo[d] += __shfl_xor(aLo[d], 16); aHi[d] += __shfl_xor(aHi[d], 16);
        aLo[d] += __shfl_xor(aLo[d], 32); aHi[d] += __shfl_xor(aHi[d], 32);
    }
    if (o == 0) {
        uint4 s = *(const uint4*)(yh + (size_t)wid * 64 + r * 8);
        float4 bA = *(const float4*)(bh + r * 8);
        float4 bB = *(const float4*)(bh + r * 8 + 4);
        float v0 = fmaxf(aLo[0] + bflo(s.x) + bA.x, 0.f);
        float v1 = fmaxf(aHi[0] + bfhi(s.x) + bA.y, 0.f);
        float v2 = fmaxf(aLo[1] + bflo(s.y) + bA.z, 0.f);
        float v3 = fmaxf(aHi[1] + bfhi(s.y) + bA.w, 0.f);
        float v4 = fmaxf(aLo[2] + bflo(s.z) + bB.x, 0.f);
        float v5 = fmaxf(aHi[2] + bfhi(s.z) + bB.y, 0.f);
        float v6 = fmaxf(aLo[3] + bflo(s.w) + bB.z, 0.f);
        float v7 = fmaxf(aHi[3] + bfhi(s.w) + bB.w, 0.f);
        uint4 out;
        out.x = (uint)f2b(v0) | ((uint)f2b(v1) << 16);
        out.y = (uint)f2b(v2) | ((uint)f2b(v3) << 16);
        out.z = (uint)f2b(v4) | ((uint)f2b(v5) << 16);
        out.w = (uint)f2b(v6) | ((uint)f2b(v7) << 16);
        *(uint4*)(hh + (size_t)wid * 64 + r * 8) = out;
    }
}

// Layer 2: y2 [NN+1][64] bf16 rows are 128B -> same oct structure, fp32 out, no relu.
__global__ __launch_bounds__(256) void agg2_k(const ushort* __restrict__ y2,
                                              const int* __restrict__ nodeptr,
                                              const uint* __restrict__ col,
                                              const float* __restrict__ b2,
                                              float* __restrict__ out) {
    int wid = (blockIdx.x * 256 + threadIdx.x) >> 6;
    int lane = threadIdx.x & 63;
    if (wid >= NN) return;
    int s0 = nodeptr[wid], s1 = nodeptr[wid + 1];
    int o = lane >> 3, r = lane & 7;

    float aLo[4] = {}, aHi[4] = {};
    const ushort* yr = y2 + r * 8;

    for (int i = s0; i < s1; i += 64) {
        int m = s1 - i; if (m > 64) m = 64;
        int sv = (lane < m) ? (int)col[i + lane] : NN;
        int jg = (m + 31) >> 5;
        for (int g = 0; g < jg; ++g) {
            int e0 = 32 * g + o;
            int sj0 = __shfl(sv, e0);
            int sj1 = __shfl(sv, e0 + 8);
            int sj2 = __shfl(sv, e0 + 16);
            int sj3 = __shfl(sv, e0 + 24);
            uint4 u0 = *(const uint4*)(yr + (size_t)sj0 * 64);
            uint4 u1 = *(const uint4*)(yr + (size_t)sj1 * 64);
            uint4 u2 = *(const uint4*)(yr + (size_t)sj2 * 64);
            uint4 u3 = *(const uint4*)(yr + (size_t)sj3 * 64);
            aLo[0] += bflo(u0.x); aHi[0] += bfraw(u0.x);
            aLo[1] += bflo(u0.y); aHi[1] += bfraw(u0.y);
            aLo[2] += bflo(u0.z); aHi[2] += bfraw(u0.z);
            aLo[3] += bflo(u0.w); aHi[3] += bfraw(u0.w);
            aLo[0] += bflo(u1.x); aHi[0] += bfraw(u1.x);
            aLo[1] += bflo(u1.y); aHi[1] += bfraw(u1.y);
            aLo[2] += bflo(u1.z); aHi[2] += bfraw(u1.z);
            aLo[3] += bflo(u1.w); aHi[3] += bfraw(u1.w);
            aLo[0] += bflo(u2.x); aHi[0] += bfraw(u2.x);
            aLo[1] += bflo(u2.y); aHi[1] += bfraw(u2.y);
            aLo[2] += bflo(u2.z); aHi[2] += bfraw(u2.z);
            aLo[3] += bflo(u2.w); aHi[3] += bfraw(u2.w);
            aLo[0] += bflo(u3.x); aHi[0] += bfraw(u3.x);
            aLo[1] += bflo(u3.y); aHi[1] += bfraw(u3.y);
            aLo[2] += bflo(u3.z); aHi[2] += bfraw(u3.z);
            aLo[3] += bflo(u3.w); aHi[3] += bfraw(u3.w);
        }
    }
#pragma unroll
    for (int d = 0; d < 4; ++d) {
        aLo[d] += __shfl_xor(aLo[d], 8);  aHi[d] += __shfl_xor(aHi[d], 8);
        aLo[d] += __shfl_xor(aLo[d], 16); aHi[d] += __shfl_xor(aHi[d], 16);
        aLo[d] += __shfl_xor(aLo[d], 32); aHi[d] += __shfl_xor(aHi[d], 32);
    }
    if (o == 0) {
        uint4 s = *(const uint4*)(y2 + (size_t)wid * 64 + r * 8);
        float4 bA = *(const float4*)(b2 + r * 8);
        float4 bB = *(const float4*)(b2 + r * 8 + 4);
        float4 o0, o1;
        o0.x = aLo[0] + bflo(s.x) + bA.x;
        o0.y = aHi[0] + bfhi(s.x) + bA.y;
        o0.z = aLo[1] + bflo(s.y) + bA.z;
        o0.w = aHi[1] + bfhi(s.y) + bA.w;
        o1.x = aLo[2] + bflo(s.z) + bB.x;
        o1.y = aHi[2] + bfhi(s.z) + bB.y;
        o1.z = aLo[3] + bflo(s.w) + bB.z;
        o1.w = aHi[3] + bfhi(s.w) + bB.w;
        *(float4*)(out + (size_t)wid * 64 + r * 8)     = o0;
        *(float4*)(out + (size_t)wid * 64 + r * 8 + 4) = o1;
    }
}

// ---------------- launch ----------------

static constexpr size_t alup(size_t x) { return (x + 255) & ~(size_t)255; }
static constexpr size_t OFF_HIST  = 0;
static constexpr size_t OFF_PBASE = alup(OFF_HIST  + (size_t)NB * NBK * 4);
static constexpr size_t OFF_TOT   = alup(OFF_PBASE + (size_t)NB * NBK * 4);
static constexpr size_t OFF_GBASE = alup(OFF_TOT   + NBK * 4);
static constexpr size_t OFF_NPTR  = alup(OFF_GBASE + (NBK + 1) * 4);
static constexpr size_t OFF_BARR  = alup(OFF_NPTR  + (size_t)(NN + 1) * 4);
static constexpr size_t OFF_COL   = alup(OFF_BARR  + (size_t)NE * 4);
static constexpr size_t OFF_Y1A   = alup(OFF_COL   + (size_t)NE * 4);
static constexpr size_t OFF_Y1B   = alup(OFF_Y1A + (size_t)(NN + 1) * 64 * 2);
static constexpr size_t OFF_HA    = alup(OFF_Y1B + (size_t)(NN + 1) * 64 * 2);
static constexpr size_t OFF_HB    = alup(OFF_HA  + (size_t)(NN + 1) * 64 * 2);
static constexpr size_t OFF_Y2    = alup(OFF_HB  + (size_t)(NN + 1) * 64 * 2);

extern "C" void kernel_launch(void* const* d_in, const int* in_sizes, int n_in,
                              void* d_out, int out_size, void* d_ws, size_t ws_size,
                              hipStream_t stream) {
    const float* x  = (const float*)d_in[0];
    const int*   ei = (const int*)d_in[1];
    const float* W1 = (const float*)d_in[2];
    const float* b1 = (const float*)d_in[3];
    const float* W2 = (const float*)d_in[4];
    const float* b2 = (const float*)d_in[5];
    float* out = (float*)d_out;
    char* ws = (char*)d_ws;

    int*  hist  = (int*)(ws + OFF_HIST);
    int*  pbase = (int*)(ws + OFF_PBASE);
    int*  tot   = (int*)(ws + OFF_TOT);
    int*  gbase = (int*)(ws + OFF_GBASE);
    int*  nptr  = (int*)(ws + OFF_NPTR);
    uint* barr  = (uint*)(ws + OFF_BARR);
    uint* colA  = (uint*)(ws + OFF_COL);
    ushort* y1a = (ushort*)(ws + OFF_Y1A);
    ushort* y1b = (ushort*)(ws + OFF_Y1B);
    ushort* ha  = (ushort*)(ws + OFF_HA);
    ushort* hb  = (ushort*)(ws + OFF_HB);
    ushort* y2  = (ushort*)(ws + OFF_Y2);

    hipLaunchKernelGGL(hist2_k,  dim3(NB),  dim3(512),  0, stream, ei, hist);
    hipLaunchKernelGGL(pbase_k,  dim3(NBK), dim3(64),   0, stream, hist, pbase, tot);
    hipLaunchKernelGGL(bscan_k,  dim3(1),   dim3(1024), 0, stream, tot, gbase, nptr, y1a, y1b, y2);
    hipLaunchKernelGGL(bfill2_k, dim3(NB),  dim3(512),  0, stream, ei, pbase, gbase, barr);
    hipLaunchKernelGGL(csr_k,    dim3(NBK), dim3(256),  0, stream, barr, gbase, nptr, colA);

    hipLaunchKernelGGL(gemm1_k, dim3(782),  dim3(256), 0, stream, x, W1, y1a, y1b);
    hipLaunchKernelGGL(agg1h_k, dim3(25000),dim3(256), 0, stream, y1a, nptr, colA, b1,      ha);
    hipLaunchKernelGGL(agg1h_k, dim3(25000),dim3(256), 0, stream, y1b, nptr, colA, b1 + 64, hb);
    hipLaunchKernelGGL(gemm2_k, dim3(782),  dim3(256), 0, stream, ha, hb, W2, y2);
    hipLaunchKernelGGL(agg2_k,  dim3(25000),dim3(256), 0, stream, y2, nptr, colA, b2, out);
}

// Round 9
// 246.355 us; speedup vs baseline: 19.8723x; 1.0488x over previous
//
#include <hip/hip_runtime.h>
#include <stdint.h>

#define NN 100000
#define NE 3200000
#define NBK 391          // ceil(NN/256) buckets of 256 dst nodes
#define NB  256          // sort blocks
#define CH  12500        // edges per sort block: 256*12500 = 3.2M = NE
#define CSRCAP 8960      // LDS staging capacity per bucket (mean 8184, sigma ~90)

typedef unsigned int uint;
typedef unsigned short ushort;
typedef __attribute__((ext_vector_type(8))) short bf16x8;
typedef __attribute__((ext_vector_type(4))) float f32x4;

static __device__ __forceinline__ float bflo(uint v) {
    uint u = v << 16; return __builtin_bit_cast(float, u);
}
static __device__ __forceinline__ float bfhi(uint v) {
    uint u = v & 0xffff0000u; return __builtin_bit_cast(float, u);
}
static __device__ __forceinline__ float bfraw(uint v) {   // hi bf16 with low-bit junk (<=2^-9 rel)
    return __builtin_bit_cast(float, v);
}
static __device__ __forceinline__ ushort f2b(float f) {  // RNE fp32->bf16
    uint u = __builtin_bit_cast(uint, f);
    u += 0x7fffu + ((u >> 16) & 1u);
    return (ushort)(u >> 16);
}
static __device__ __forceinline__ int wscan(int v, int lane) {  // 64-lane inclusive
#pragma unroll
    for (int off = 1; off < 64; off <<= 1) {
        int t = __shfl_up(v, off);
        if (lane >= off) v += t;
    }
    return v;
}

// ---------------- deterministic bucket counting-sort ----------------

__global__ __launch_bounds__(512) void hist2_k(const int* __restrict__ ei,
                                               int* __restrict__ hist) {
    __shared__ int hl[NBK];
    int tid = threadIdx.x, b = blockIdx.x;
    for (int k = tid; k < NBK; k += 512) hl[k] = 0;
    __syncthreads();
    int base = b * CH;
    for (int i = base + tid; i < base + CH; i += 512)
        atomicAdd(&hl[ei[NE + i] >> 8], 1);
    __syncthreads();
    for (int k = tid; k < NBK; k += 512) hist[b * NBK + k] = hl[k];
}

__global__ __launch_bounds__(64) void pbase_k(const int* __restrict__ hist,
                                              int* __restrict__ pbase,
                                              int* __restrict__ totals) {
    int k = blockIdx.x, lane = threadIdx.x;
    int carry = 0;
#pragma unroll
    for (int c = 0; c < NB / 64; ++c) {
        int b = c * 64 + lane;
        int v = hist[b * NBK + k];
        int incl = wscan(v, lane);
        pbase[b * NBK + k] = carry + incl - v;
        carry += __shfl(incl, 63);
    }
    if (lane == 0) totals[k] = carry;
}

// scan bucket totals -> gbase; also zero the pad rows (index NN) of y1a/y1b/y2.
__global__ __launch_bounds__(1024) void bscan_k(const int* __restrict__ totals,
                                                int* __restrict__ gbase,
                                                int* __restrict__ nodeptr,
                                                ushort* __restrict__ y1a,
                                                ushort* __restrict__ y1b,
                                                ushort* __restrict__ y2) {
    __shared__ int sd[1024];
    int t = threadIdx.x;
    int v = (t < NBK) ? totals[t] : 0;
    sd[t] = v;
    __syncthreads();
    for (int off = 1; off < 1024; off <<= 1) {
        int u = (t >= off) ? sd[t - off] : 0;
        __syncthreads();
        sd[t] += u;
        __syncthreads();
    }
    int excl = sd[t] - v;
    if (t < NBK) gbase[t] = excl;
    if (t == 0) { gbase[NBK] = NE; nodeptr[NN] = NE; }
    if (t < 32)              ((uint*)(y1a + (size_t)NN * 64))[t] = 0;
    else if (t < 64)         ((uint*)(y1b + (size_t)NN * 64))[t - 32] = 0;
    else if (t < 96)         ((uint*)(y2  + (size_t)NN * 64))[t - 64] = 0;
}

// direct scatter with LDS cursors seeded from gbase+pbase.
// Runs per (block,bucket) ~= 32 edges = 128B -> full-line writes.
__global__ __launch_bounds__(512) void bfill2_k(const int* __restrict__ ei,
                                                const int* __restrict__ pbase,
                                                const int* __restrict__ gbase,
                                                uint* __restrict__ barr) {
    __shared__ int cur[NBK];
    int tid = threadIdx.x, b = blockIdx.x;
    for (int k = tid; k < NBK; k += 512)
        cur[k] = gbase[k] + pbase[b * NBK + k];
    __syncthreads();
    int base = b * CH;
    for (int i = base + tid; i < base + CH; i += 512) {
        int s = ei[i], d = ei[NE + i];
        int pos = atomicAdd(&cur[d >> 8], 1);       // LDS atomic only
        barr[pos] = ((uint)(d & 255) << 17) | (uint)s;
    }
}

// within-bucket counting sort via LDS staging (single global read of the bucket).
__global__ __launch_bounds__(256) void csr_k(const uint* __restrict__ barr,
                                             const int* __restrict__ gbase,
                                             int* __restrict__ nodeptr,
                                             uint* __restrict__ col) {
    __shared__ uint stg[CSRCAP];
    __shared__ int cnt[256], cur[256];
    int tid = threadIdx.x;
    int blk = blockIdx.x;
    int s0 = gbase[blk], s1 = gbase[blk + 1];
    int n = s1 - s0;
    bool fits = (n <= CSRCAP);
    cnt[tid] = 0;
    __syncthreads();
    if (fits) {
        for (int i = tid; i < n; i += 256) {
            uint e = barr[s0 + i];
            stg[i] = e;
            atomicAdd(&cnt[e >> 17], 1);
        }
    } else {
        for (int i = s0 + tid; i < s1; i += 256)
            atomicAdd(&cnt[barr[i] >> 17], 1);
    }
    __syncthreads();
    if (tid < 64) {
        int c0 = cnt[4 * tid], c1 = cnt[4 * tid + 1];
        int c2 = cnt[4 * tid + 2], c3 = cnt[4 * tid + 3];
        int s = c0 + c1 + c2 + c3;
        int incl = wscan(s, tid);
        int excl = incl - s;
        cur[4 * tid]     = excl;
        cur[4 * tid + 1] = excl + c0;
        cur[4 * tid + 2] = excl + c0 + c1;
        cur[4 * tid + 3] = excl + c0 + c1 + c2;
        int node = blk * 256 + 4 * tid;
        if (node < NN)     nodeptr[node]     = s0 + excl;
        if (node + 1 < NN) nodeptr[node + 1] = s0 + excl + c0;
        if (node + 2 < NN) nodeptr[node + 2] = s0 + excl + c0 + c1;
        if (node + 3 < NN) nodeptr[node + 3] = s0 + excl + c0 + c1 + c2;
    }
    __syncthreads();
    if (fits) {
        for (int i = tid; i < n; i += 256) {
            uint e = stg[i];
            int pos = s0 + atomicAdd(&cur[e >> 17], 1);
            col[pos] = e & 0x1FFFF;
        }
    } else {
        for (int i = s0 + tid; i < s1; i += 256) {
            uint e = barr[i];
            int pos = s0 + atomicAdd(&cur[e >> 17], 1);
            col[pos] = e & 0x1FFFF;
        }
    }
}

// ---------------- GEMM1: y1 = bf16( x @ W1^T ), planar halves ----------------
__global__ __launch_bounds__(256) void gemm1_k(const float* __restrict__ x,
                                               const float* __restrict__ W1,
                                               ushort* __restrict__ y1a,
                                               ushort* __restrict__ y1b) {
    __shared__ ushort wl[128 * 136];
    int tid = threadIdx.x;
    for (int i = tid; i < 128 * 128; i += 256)
        wl[(i >> 7) * 136 + (i & 127)] = f2b(W1[i]);
    __syncthreads();

    int wave = tid >> 6, lane = tid & 63;
    int lr = lane & 15, lk = (lane >> 4) * 8;
    long rowbase = (long)blockIdx.x * 128 + wave * 32;

    f32x4 acc[2][8] = {};
    for (int kc = 0; kc < 128; kc += 32) {
        bf16x8 a[2];
#pragma unroll
        for (int m = 0; m < 2; m++) {
            long row = rowbase + m * 16 + lr;
            if (row > NN - 1) row = NN - 1;
            const float* p = x + row * 128 + kc + lk;
            float f[8];
            *(float4*)(f)     = *(const float4*)(p);
            *(float4*)(f + 4) = *(const float4*)(p + 4);
            bf16x8 t;
#pragma unroll
            for (int j = 0; j < 8; j++) t[j] = (short)f2b(f[j]);
            a[m] = t;
        }
#pragma unroll
        for (int nb = 0; nb < 8; nb++) {
            bf16x8 b = *(const bf16x8*)&wl[(nb * 16 + lr) * 136 + kc + lk];
            acc[0][nb] = __builtin_amdgcn_mfma_f32_16x16x32_bf16(a[0], b, acc[0][nb], 0, 0, 0);
            acc[1][nb] = __builtin_amdgcn_mfma_f32_16x16x32_bf16(a[1], b, acc[1][nb], 0, 0, 0);
        }
    }
    int rq = (lane >> 4) * 4;
#pragma unroll
    for (int m = 0; m < 2; m++) {
#pragma unroll
        for (int r = 0; r < 4; r++) {
            long row = rowbase + m * 16 + rq + r;
            if (row < NN) {
#pragma unroll
                for (int nb = 0; nb < 8; nb++) {
                    ushort v = f2b(acc[m][nb][r]);
                    if (nb < 4) y1a[row * 64 + nb * 16 + lr] = v;
                    else        y1b[row * 64 + (nb - 4) * 16 + lr] = v;
                }
            }
        }
    }
}

// ---------------- GEMM2: y2 = bf16( h @ W2^T ), h in planar halves ----------------
__global__ __launch_bounds__(256) void gemm2_k(const ushort* __restrict__ ha,
                                               const ushort* __restrict__ hb,
                                               const float* __restrict__ W2,
                                               ushort* __restrict__ y2) {
    __shared__ ushort wl[64 * 136];
    int tid = threadIdx.x;
    for (int i = tid; i < 64 * 128; i += 256)
        wl[(i >> 7) * 136 + (i & 127)] = f2b(W2[i]);
    __syncthreads();

    int wave = tid >> 6, lane = tid & 63;
    int lr = lane & 15, lk = (lane >> 4) * 8;
    long rowbase = (long)blockIdx.x * 128 + wave * 32;

    f32x4 acc[2][4] = {};
#pragma unroll
    for (int kc = 0; kc < 128; kc += 32) {
        const ushort* hsrc = (kc < 64) ? ha : hb;
        int koff = kc & 63;
        bf16x8 a[2];
#pragma unroll
        for (int m = 0; m < 2; m++) {
            long row = rowbase + m * 16 + lr;
            if (row > NN - 1) row = NN - 1;
            a[m] = *(const bf16x8*)(hsrc + row * 64 + koff + lk);
        }
#pragma unroll
        for (int nb = 0; nb < 4; nb++) {
            bf16x8 b = *(const bf16x8*)&wl[(nb * 16 + lr) * 136 + kc + lk];
            acc[0][nb] = __builtin_amdgcn_mfma_f32_16x16x32_bf16(a[0], b, acc[0][nb], 0, 0, 0);
            acc[1][nb] = __builtin_amdgcn_mfma_f32_16x16x32_bf16(a[1], b, acc[1][nb], 0, 0, 0);
        }
    }
    int rq = (lane >> 4) * 4;
#pragma unroll
    for (int m = 0; m < 2; m++) {
#pragma unroll
        for (int r = 0; r < 4; r++) {
            long row = rowbase + m * 16 + rq + r;
            if (row < NN) {
#pragma unroll
                for (int nb = 0; nb < 4; nb++)
                    y2[row * 64 + nb * 16 + lr] = f2b(acc[m][nb][r]);
            }
        }
    }
}

// ---------------- pull aggregation: wave per node, OCT (8 lanes) per edge ----------------

__global__ __launch_bounds__(256) void agg1h_k(const ushort* __restrict__ yh,
                                               const int* __restrict__ nodeptr,
                                               const uint* __restrict__ col,
                                               const float* __restrict__ bh,
                                               ushort* __restrict__ hh) {
    int wid = (blockIdx.x * 256 + threadIdx.x) >> 6;
    int lane = threadIdx.x & 63;
    if (wid >= NN) return;
    int s0 = nodeptr[wid], s1 = nodeptr[wid + 1];
    int o = lane >> 3, r = lane & 7;

    float aLo[4] = {}, aHi[4] = {};
    const ushort* yr = yh + r * 8;

    for (int i = s0; i < s1; i += 64) {
        int m = s1 - i; if (m > 64) m = 64;
        int sv = (lane < m) ? (int)col[i + lane] : NN;
        int jg = (m + 31) >> 5;                    // groups of 32 edges
        for (int g = 0; g < jg; ++g) {
            int e0 = 32 * g + o;
            int sj0 = __shfl(sv, e0);
            int sj1 = __shfl(sv, e0 + 8);
            int sj2 = __shfl(sv, e0 + 16);
            int sj3 = __shfl(sv, e0 + 24);
            uint4 u0 = *(const uint4*)(yr + (size_t)sj0 * 64);
            uint4 u1 = *(const uint4*)(yr + (size_t)sj1 * 64);
            uint4 u2 = *(const uint4*)(yr + (size_t)sj2 * 64);
            uint4 u3 = *(const uint4*)(yr + (size_t)sj3 * 64);
            aLo[0] += bflo(u0.x); aHi[0] += bfraw(u0.x);
            aLo[1] += bflo(u0.y); aHi[1] += bfraw(u0.y);
            aLo[2] += bflo(u0.z); aHi[2] += bfraw(u0.z);
            aLo[3] += bflo(u0.w); aHi[3] += bfraw(u0.w);
            aLo[0] += bflo(u1.x); aHi[0] += bfraw(u1.x);
            aLo[1] += bflo(u1.y); aHi[1] += bfraw(u1.y);
            aLo[2] += bflo(u1.z); aHi[2] += bfraw(u1.z);
            aLo[3] += bflo(u1.w); aHi[3] += bfraw(u1.w);
            aLo[0] += bflo(u2.x); aHi[0] += bfraw(u2.x);
            aLo[1] += bflo(u2.y); aHi[1] += bfraw(u2.y);
            aLo[2] += bflo(u2.z); aHi[2] += bfraw(u2.z);
            aLo[3] += bflo(u2.w); aHi[3] += bfraw(u2.w);
            aLo[0] += bflo(u3.x); aHi[0] += bfraw(u3.x);
            aLo[1] += bflo(u3.y); aHi[1] += bfraw(u3.y);
            aLo[2] += bflo(u3.z); aHi[2] += bfraw(u3.z);
            aLo[3] += bflo(u3.w); aHi[3] += bfraw(u3.w);
        }
    }
#pragma unroll
    for (int d = 0; d < 4; ++d) {
        aLo[d] += __shfl_xor(aLo[d], 8);  aHi[d] += __shfl_xor(aHi[d], 8);
        aLo[d] += __shfl_xor(aLo[d], 16); aHi[d] += __shfl_xor(aHi[d], 16);
        aLo[d] += __shfl_xor(aLo[d], 32); aHi[d] += __shfl_xor(aHi[d], 32);
    }
    if (o == 0) {
        uint4 s = *(const uint4*)(yh + (size_t)wid * 64 + r * 8);
        float4 bA = *(const float4*)(bh + r * 8);
        float4 bB = *(const float4*)(bh + r * 8 + 4);
        float v0 = fmaxf(aLo[0] + bflo(s.x) + bA.x, 0.f);
        float v1 = fmaxf(aHi[0] + bfhi(s.x) + bA.y, 0.f);
        float v2 = fmaxf(aLo[1] + bflo(s.y) + bA.z, 0.f);
        float v3 = fmaxf(aHi[1] + bfhi(s.y) + bA.w, 0.f);
        float v4 = fmaxf(aLo[2] + bflo(s.z) + bB.x, 0.f);
        float v5 = fmaxf(aHi[2] + bfhi(s.z) + bB.y, 0.f);
        float v6 = fmaxf(aLo[3] + bflo(s.w) + bB.z, 0.f);
        float v7 = fmaxf(aHi[3] + bfhi(s.w) + bB.w, 0.f);
        uint4 out;
        out.x = (uint)f2b(v0) | ((uint)f2b(v1) << 16);
        out.y = (uint)f2b(v2) | ((uint)f2b(v3) << 16);
        out.z = (uint)f2b(v4) | ((uint)f2b(v5) << 16);
        out.w = (uint)f2b(v6) | ((uint)f2b(v7) << 16);
        *(uint4*)(hh + (size_t)wid * 64 + r * 8) = out;
    }
}

__global__ __launch_bounds__(256) void agg2_k(const ushort* __restrict__ y2,
                                              const int* __restrict__ nodeptr,
                                              const uint* __restrict__ col,
                                              const float* __restrict__ b2,
                                              float* __restrict__ out) {
    int wid = (blockIdx.x * 256 + threadIdx.x) >> 6;
    int lane = threadIdx.x & 63;
    if (wid >= NN) return;
    int s0 = nodeptr[wid], s1 = nodeptr[wid + 1];
    int o = lane >> 3, r = lane & 7;

    float aLo[4] = {}, aHi[4] = {};
    const ushort* yr = y2 + r * 8;

    for (int i = s0; i < s1; i += 64) {
        int m = s1 - i; if (m > 64) m = 64;
        int sv = (lane < m) ? (int)col[i + lane] : NN;
        int jg = (m + 31) >> 5;
        for (int g = 0; g < jg; ++g) {
            int e0 = 32 * g + o;
            int sj0 = __shfl(sv, e0);
            int sj1 = __shfl(sv, e0 + 8);
            int sj2 = __shfl(sv, e0 + 16);
            int sj3 = __shfl(sv, e0 + 24);
            uint4 u0 = *(const uint4*)(yr + (size_t)sj0 * 64);
            uint4 u1 = *(const uint4*)(yr + (size_t)sj1 * 64);
            uint4 u2 = *(const uint4*)(yr + (size_t)sj2 * 64);
            uint4 u3 = *(const uint4*)(yr + (size_t)sj3 * 64);
            aLo[0] += bflo(u0.x); aHi[0] += bfraw(u0.x);
            aLo[1] += bflo(u0.y); aHi[1] += bfraw(u0.y);
            aLo[2] += bflo(u0.z); aHi[2] += bfraw(u0.z);
            aLo[3] += bflo(u0.w); aHi[3] += bfraw(u0.w);
            aLo[0] += bflo(u1.x); aHi[0] += bfraw(u1.x);
            aLo[1] += bflo(u1.y); aHi[1] += bfraw(u1.y);
            aLo[2] += bflo(u1.z); aHi[2] += bfraw(u1.z);
            aLo[3] += bflo(u1.w); aHi[3] += bfraw(u1.w);
            aLo[0] += bflo(u2.x); aHi[0] += bfraw(u2.x);
            aLo[1] += bflo(u2.y); aHi[1] += bfraw(u2.y);
            aLo[2] += bflo(u2.z); aHi[2] += bfraw(u2.z);
            aLo[3] += bflo(u2.w); aHi[3] += bfraw(u2.w);
            aLo[0] += bflo(u3.x); aHi[0] += bfraw(u3.x);
            aLo[1] += bflo(u3.y); aHi[1] += bfraw(u3.y);
            aLo[2] += bflo(u3.z); aHi[2] += bfraw(u3.z);
            aLo[3] += bflo(u3.w); aHi[3] += bfraw(u3.w);
        }
    }
#pragma unroll
    for (int d = 0; d < 4; ++d) {
        aLo[d] += __shfl_xor(aLo[d], 8);  aHi[d] += __shfl_xor(aHi[d], 8);
        aLo[d] += __shfl_xor(aLo[d], 16); aHi[d] += __shfl_xor(aHi[d], 16);
        aLo[d] += __shfl_xor(aLo[d], 32); aHi[d] += __shfl_xor(aHi[d], 32);
    }
    if (o == 0) {
        uint4 s = *(const uint4*)(y2 + (size_t)wid * 64 + r * 8);
        float4 bA = *(const float4*)(b2 + r * 8);
        float4 bB = *(const float4*)(b2 + r * 8 + 4);
        float4 o0, o1;
        o0.x = aLo[0] + bflo(s.x) + bA.x;
        o0.y = aHi[0] + bfhi(s.x) + bA.y;
        o0.z = aLo[1] + bflo(s.y) + bA.z;
        o0.w = aHi[1] + bfhi(s.y) + bA.w;
        o1.x = aLo[2] + bflo(s.z) + bB.x;
        o1.y = aHi[2] + bfhi(s.z) + bB.y;
        o1.z = aLo[3] + bflo(s.w) + bB.z;
        o1.w = aHi[3] + bfhi(s.w) + bB.w;
        *(float4*)(out + (size_t)wid * 64 + r * 8)     = o0;
        *(float4*)(out + (size_t)wid * 64 + r * 8 + 4) = o1;
    }
}

// ---------------- launch ----------------

static constexpr size_t alup(size_t x) { return (x + 255) & ~(size_t)255; }
static constexpr size_t OFF_HIST  = 0;
static constexpr size_t OFF_PBASE = alup(OFF_HIST  + (size_t)NB * NBK * 4);
static constexpr size_t OFF_TOT   = alup(OFF_PBASE + (size_t)NB * NBK * 4);
static constexpr size_t OFF_GBASE = alup(OFF_TOT   + NBK * 4);
static constexpr size_t OFF_NPTR  = alup(OFF_GBASE + (NBK + 1) * 4);
static constexpr size_t OFF_BARR  = alup(OFF_NPTR  + (size_t)(NN + 1) * 4);
static constexpr size_t OFF_COL   = alup(OFF_BARR  + (size_t)NE * 4);
static constexpr size_t OFF_Y1A   = alup(OFF_COL   + (size_t)NE * 4);
static constexpr size_t OFF_Y1B   = alup(OFF_Y1A + (size_t)(NN + 1) * 64 * 2);
static constexpr size_t OFF_HA    = alup(OFF_Y1B + (size_t)(NN + 1) * 64 * 2);
static constexpr size_t OFF_HB    = alup(OFF_HA  + (size_t)(NN + 1) * 64 * 2);
static constexpr size_t OFF_Y2    = alup(OFF_HB  + (size_t)(NN + 1) * 64 * 2);

extern "C" void kernel_launch(void* const* d_in, const int* in_sizes, int n_in,
                              void* d_out, int out_size, void* d_ws, size_t ws_size,
                              hipStream_t stream) {
    const float* x  = (const float*)d_in[0];
    const int*   ei = (const int*)d_in[1];
    const float* W1 = (const float*)d_in[2];
    const float* b1 = (const float*)d_in[3];
    const float* W2 = (const float*)d_in[4];
    const float* b2 = (const float*)d_in[5];
    float* out = (float*)d_out;
    char* ws = (char*)d_ws;

    int*  hist  = (int*)(ws + OFF_HIST);
    int*  pbase = (int*)(ws + OFF_PBASE);
    int*  tot   = (int*)(ws + OFF_TOT);
    int*  gbase = (int*)(ws + OFF_GBASE);
    int*  nptr  = (int*)(ws + OFF_NPTR);
    uint* barr  = (uint*)(ws + OFF_BARR);
    uint* colA  = (uint*)(ws + OFF_COL);
    ushort* y1a = (ushort*)(ws + OFF_Y1A);
    ushort* y1b = (ushort*)(ws + OFF_Y1B);
    ushort* ha  = (ushort*)(ws + OFF_HA);
    ushort* hb  = (ushort*)(ws + OFF_HB);
    ushort* y2  = (ushort*)(ws + OFF_Y2);

    hipLaunchKernelGGL(hist2_k,  dim3(NB),  dim3(512),  0, stream, ei, hist);
    hipLaunchKernelGGL(pbase_k,  dim3(NBK), dim3(64),   0, stream, hist, pbase, tot);
    hipLaunchKernelGGL(bscan_k,  dim3(1),   dim3(1024), 0, stream, tot, gbase, nptr, y1a, y1b, y2);
    hipLaunchKernelGGL(bfill2_k, dim3(NB),  dim3(512),  0, stream, ei, pbase, gbase, barr);
    hipLaunchKernelGGL(csr_k,    dim3(NBK), dim3(256),  0, stream, barr, gbase, nptr, colA);

    hipLaunchKernelGGL(gemm1_k, dim3(782),  dim3(256), 0, stream, x, W1, y1a, y1b);
    hipLaunchKernelGGL(agg1h_k, dim3(25000),dim3(256), 0, stream, y1a, nptr, colA, b1,      ha);
    hipLaunchKernelGGL(agg1h_k, dim3(25000),dim3(256), 0, stream, y1b, nptr, colA, b1 + 64, hb);
    hipLaunchKernelGGL(gemm2_k, dim3(782),  dim3(256), 0, stream, ha, hb, W2, y2);
    hipLaunchKernelGGL(agg2_k,  dim3(25000),dim3(256), 0, stream, y2, nptr, colA, b2, out);
}